// Round 1
// baseline (291.682 us; speedup 1.0000x reference)
//
#include <hip/hip_runtime.h>
#include <math.h>

// Problem constants: B=1, C=64, D=H=W=16, HEADS=4, HD=16
#define CN   262144        // C * 4096 floats per [C, D, H, W] tensor
#define BTP 196            // qkv/conv Bt row stride in bf16
#define PTP 68             // proj Bt row stride in bf16

typedef __attribute__((ext_vector_type(8))) short short8;   // 8 bf16 (4 VGPRs)
typedef __attribute__((ext_vector_type(4))) short short4v;  // 8 B
typedef __attribute__((ext_vector_type(4))) float float4v;  // MFMA C/D

static __device__ __forceinline__ unsigned short f2bf(float f) {
    union { float f; unsigned u; } v; v.f = f;
    unsigned r = (v.u + 0x7FFFu + ((v.u >> 16) & 1u)) >> 16;   // RNE
    return (unsigned short)r;
}

// Device-scope grid barrier. Monotonic target (no counter reset between
// phases); counter is zeroed by a hipMemsetAsync node before the kernel each
// graph replay. Co-residency of all 512 blocks is guaranteed by
// __launch_bounds__(512,4): <=128 VGPR -> 16 waves/CU -> 2 blocks/CU x 256 CU.
// Bounded spin: on failure we produce a wrong answer instead of a hang.
static __device__ __forceinline__ void grid_bar(int* bar, int target) {
    __syncthreads();                         // all block threads arrived, vmem drained
    if (threadIdx.x == 0) {
        __threadfence();                     // agent-scope release (L2 writeback)
        atomicAdd(bar, 1);                   // device-scope by default
        int z = 0;
        while (__hip_atomic_load(bar, __ATOMIC_RELAXED, __HIP_MEMORY_SCOPE_AGENT) < target
               && z < (1 << 22)) {
            __builtin_amdgcn_s_sleep(1);
            ++z;
        }
        __threadfence();                     // agent-scope acquire (L1/L2 invalidate)
    }
    __syncthreads();
}

// ---------------------------------------------------------------------------
// Mega-kernel: all 5 pipeline stages, separated by grid barriers instead of
// kernel boundaries. Stage bodies are bit-identical to the 5-kernel version
// (r16-verified numerics preserved).
// Grid 512 x 512 threads; LDS union = max(stage LDS) = 32.9 KB.
__global__ __launch_bounds__(512, 4) void mega_kernel(
        const float* __restrict__ x, const float* __restrict__ gamma,
        const float* __restrict__ w_sp, const float* __restrict__ b_sp,
        const float* __restrict__ w_spec, const float* __restrict__ b_spec,
        const float* __restrict__ w_qkv, const float* __restrict__ b_qkv,
        const float* __restrict__ w_proj, const float* __restrict__ b_proj,
        float* __restrict__ out, float* ws, int* bar) {
    // LDS union: conv Bt 6.3KB | qkv Bt 12.5KB | attn ksh16K+vsh16K+gp128 | proj 2.2KB
    __shared__ __align__(16) unsigned char lds_raw[32896];

    float* y1  = ws;                                        // [64][4096] f32
    unsigned short* wfb = (unsigned short*)(ws + CN);       // [192][192] bf16
    float* bfv = ws + CN + 20480;                           // [192] fused bias f32
    unsigned short* wsb = (unsigned short*)(ws + CN + 24576); // [3][64][192] bf16
    unsigned short* qb  = (unsigned short*)(ws + 2 * CN);
    unsigned short* kb  = (unsigned short*)(ws + 2 * CN + CN / 2);
    unsigned short* vtb = (unsigned short*)(ws + 3 * CN);
    float* aoall = ws + 3 * CN + CN / 2;                    // 8 x [64][4096]

    // ---- S0: weight prep (was wprep_kernel, 144x512 = 73728 items) ----
    {
        int idx = blockIdx.x * 512 + threadIdx.x;           // 0..262143
        if (idx < 36864) {
            int dh  = idx / 12288;
            int rem = idx % 12288;
            int co  = rem / 192;
            int kp  = rem % 192;                            // = ci*3 + dw
            int ci = kp / 3, dw = kp % 3;
            wsb[idx] = f2bf(w_sp[co * 576 + ci * 9 + dh * 3 + dw]);
        } else if (idx < 73728) {
            int j = idx - 36864;                            // 0..36863
            int oc = j / 192;
            int r  = j % 192;                               // = cj*3 + t
            float s = 0.f;
            #pragma unroll 8
            for (int ci = 0; ci < 64; ++ci)
                s += w_qkv[oc * 64 + ci] * w_spec[ci * 192 + r];
            if (oc < 64) s *= 0.25f;
            wfb[oc * 192 + r] = f2bf(s);
            if (j < 192) {
                float t = b_qkv[j];
                for (int ci = 0; ci < 64; ++ci) t += w_qkv[j * 64 + ci] * b_spec[ci];
                if (j < 64) t *= 0.25f;
                bfv[j] = t;
            }
        }
    }
    grid_bar(bar, 512);

    // ---- S1: spatial conv 3x3 (was conv_sp_mfma_kernel, 256 blocks x 256) ----
    if (blockIdx.x < 256) {
        unsigned short* Bt = (unsigned short*)lds_raw;      // [16][BTP]
        int d = blockIdx.x >> 4;
        int h = blockIdx.x & 15;
        int tid = threadIdx.x;
        bool act = tid < 256;                               // waves 0-3 active
        int px = tid & 15, cig = (tid >> 4) & 15;

        float rcur[12], rnxt[12];
        #define LOAD_CHUNK(dh_, rr)                                            \
            {                                                                  \
                int hh = h + (dh_) - 1;                                        \
                _Pragma("unroll")                                              \
                for (int cc = 0; cc < 4; ++cc) {                               \
                    int ci = cig * 4 + cc;                                     \
                    const float* xr = x + ci * 4096 + d * 256 + hh * 16;       \
                    _Pragma("unroll")                                          \
                    for (int dw = 0; dw < 3; ++dw) {                           \
                        int ww = px + dw - 1;                                  \
                        float v = 0.f;                                         \
                        if (hh >= 0 && hh <= 15 && ww >= 0 && ww <= 15)        \
                            v = xr[ww];                                        \
                        (rr)[cc * 3 + dw] = v;                                 \
                    }                                                          \
                }                                                              \
            }

        if (act) LOAD_CHUNK(0, rcur);

        int wv = (tid >> 6) & 3, lane = tid & 63;
        int quad = lane >> 4, l15 = lane & 15;
        float4v acc = {0.f, 0.f, 0.f, 0.f};

        #pragma unroll
        for (int c = 0; c < 3; ++c) {
            __syncthreads();                 // guard Bt reuse across chunks
            if (act) {
                #pragma unroll
                for (int cc = 0; cc < 4; ++cc) {
                    int ci = cig * 4 + cc;
                    Bt[px * BTP + ci * 3 + 0] = f2bf(rcur[cc * 3 + 0]);
                    Bt[px * BTP + ci * 3 + 1] = f2bf(rcur[cc * 3 + 1]);
                    Bt[px * BTP + ci * 3 + 2] = f2bf(rcur[cc * 3 + 2]);
                }
            }
            __syncthreads();
            if (act) {
                if (c < 2) LOAD_CHUNK(c + 1, rnxt);

                const unsigned short* ab = wsb + c * 12288 + (wv * 16 + l15) * 192 + quad * 8;
                const unsigned short* brow = Bt + l15 * BTP + quad * 8;
                #pragma unroll
                for (int ks = 0; ks < 6; ++ks) {
                    short8 af = *(const short8*)(ab + ks * 32);
                    short4v lo = *(const short4v*)(brow + ks * 32);
                    short4v hi = *(const short4v*)(brow + ks * 32 + 4);
                    short8 bf8 = {lo[0], lo[1], lo[2], lo[3], hi[0], hi[1], hi[2], hi[3]};
                    acc = __builtin_amdgcn_mfma_f32_16x16x32_bf16(af, bf8, acc, 0, 0, 0);
                }
                #pragma unroll
                for (int q2 = 0; q2 < 12; ++q2) rcur[q2] = rnxt[q2];
            }
        }

        if (act) {
            int p = d * 256 + h * 16 + l15;
            #pragma unroll
            for (int r = 0; r < 4; ++r) {
                int co = wv * 16 + quad * 4 + r;
                y1[co * 4096 + p] = acc[r] + b_sp[co];
            }
        }
        #undef LOAD_CHUNK
    }
    grid_bar(bar, 1024);

    // ---- S2: spectral-conv + QKV (was qkv_mfma_kernel, 384 blocks x 512) ----
    if (blockIdx.x < 384) {
        unsigned short* Bt = (unsigned short*)lds_raw;      // [32][BTP]
        int bI  = blockIdx.x;            // 384 = 16 d x 8 pq x 3 ocg
        int ocg = bI % 3;                // 0=q 1=k 2=v
        int pq  = (bI / 3) & 7;
        int d   = bI / 24;
        int tid = threadIdx.x;

        {   // stage im2col slab: Bt[px][ci*3+t] = y1[ci][d+t-1][pq*32+px]
            int px  = tid & 31;
            int cig = tid >> 5;          // 0..15 (4 ci each)
            const float* yb = y1 + d * 256 + pq * 32 + px;
            #pragma unroll
            for (int cc = 0; cc < 4; ++cc) {
                int ci = cig * 4 + cc;
                const float* yc = yb + ci * 4096;
                #pragma unroll
                for (int t = 0; t < 3; ++t) {
                    float v = 0.f;
                    if (!((d == 0 && t == 0) || (d == 15 && t == 2)))
                        v = yc[(t - 1) * 256];
                    Bt[px * BTP + ci * 3 + t] = f2bf(v);
                }
            }
        }

        int wv = tid >> 6, lane = tid & 63;
        int quad = lane >> 4, l15 = lane & 15;
        int Mt = wv >> 1;                // 0..3 (= head)
        int nt = wv & 1;                 // N-tile (16 pos)

        short8 af[6];
        {
            const unsigned short* ab = wfb + (ocg * 64 + Mt * 16 + l15) * 192 + quad * 8;
            #pragma unroll
            for (int ks = 0; ks < 6; ++ks) af[ks] = *(const short8*)(ab + ks * 32);
        }
        float bias[4];
        #pragma unroll
        for (int r = 0; r < 4; ++r) bias[r] = bfv[ocg * 64 + Mt * 16 + quad * 4 + r];

        __syncthreads();

        float4v czero = {0.f, 0.f, 0.f, 0.f};
        float4v acc = czero;
        {
            const unsigned short* brow = Bt + (nt * 16 + l15) * BTP + quad * 8;
            #pragma unroll
            for (int ks = 0; ks < 6; ++ks) {
                short4v lo = *(const short4v*)(brow + ks * 32);
                short4v hi = *(const short4v*)(brow + ks * 32 + 4);
                short8 bf8 = {lo[0], lo[1], lo[2], lo[3], hi[0], hi[1], hi[2], hi[3]};
                acc = __builtin_amdgcn_mfma_f32_16x16x32_bf16(af[ks], bf8, acc, 0, 0, 0);
            }
        }

        {   // epilogue: C row = oc_local (quad*4+r), col = pos (l15)
            int p = d * 256 + pq * 32 + nt * 16 + l15;
            if (ocg == 2) {
                int h = (p >> 4) & 15, w0 = p & 15;
                int kap = 8 * (w0 >> 2) + 4 * (h & 1) + (w0 & 3);
                unsigned short* dst = vtb + ((Mt * 16 + d) * 8 + (h >> 1)) * 512
                                          + (quad * 4) * 32 + kap;
                #pragma unroll
                for (int r = 0; r < 4; ++r) dst[r * 32] = f2bf(acc[r] + bias[r]);
            } else {
                unsigned short* dst = (ocg == 0 ? qb : kb) + Mt * 65536 + p * 16 + quad * 4;
                unsigned t0 = (unsigned)f2bf(acc[0] + bias[0])
                            | ((unsigned)f2bf(acc[1] + bias[1]) << 16);
                unsigned t1 = (unsigned)f2bf(acc[2] + bias[2])
                            | ((unsigned)f2bf(acc[3] + bias[3]) << 16);
                *(unsigned*)dst = t0;
                *(unsigned*)(dst + 2) = t1;
            }
        }
    }
    grid_bar(bar, 1536);

    // ---- S3: retention attention (was attn_kernel, 1024 blocks x 512) ----
    // Each physical block runs 2 virtual blocks sequentially.
    {
        unsigned short* KSH = (unsigned short*)lds_raw;          // [2][4096]
        unsigned short* VSH = (unsigned short*)lds_raw + 8192;   // [2][4096]
        float* gp = (float*)(lds_raw + 32768);                   // [32]
        int tid = threadIdx.x;
        if (tid < 32) {
            float g = 1.f / (1.f + __expf(-gamma[0]));
            gp[tid] = __powf(g, (float)tid);
        }
        int wv = tid >> 6, lane = tid & 63;
        int quad = lane >> 4, l15 = lane & 15;
        short8 zero8 = {0, 0, 0, 0, 0, 0, 0, 0};
        float4v czero = {0.f, 0.f, 0.f, 0.f};

        #pragma unroll 1
        for (int it = 0; it < 2; ++it) {
            int bI = blockIdx.x + it * 512;    // virtual block 0..1023
            int head = bI >> 8;
            int mg   = (bI >> 5) & 7;
            int oct  = bI & 31;
            int t = oct * 8 + wv;
            int i = t >> 4, j = t & 15;

            short8 qf = zero8;
            if (quad < 2)
                qf = *(const short8*)(qb + head * 65536 + (t * 16 + l15) * 16 + quad * 8);

            const unsigned short* kbh = kb  + head * 65536 + mg * 2 * 4096;
            const unsigned short* vbh = vtb + head * 65536 + mg * 2 * 4096;
            float4 k0 = ((const float4*)kbh)[tid];
            float4 v0 = ((const float4*)vbh)[tid];
            float4 k1 = ((const float4*)(kbh + 4096))[tid];
            float4 v1 = ((const float4*)(vbh + 4096))[tid];
            __syncthreads();                   // prev-iter LDS readers done
            ((float4*)KSH)[tid] = k0;
            ((float4*)VSH)[tid] = v0;
            ((float4*)(KSH + 4096))[tid] = k1;
            ((float4*)(VSH + 4096))[tid] = v1;
            __syncthreads();                   // gp + both slabs ready

            float wd[4];
            #pragma unroll
            for (int r = 0; r < 4; ++r)
                wd[r] = gp[abs(l15 - (quad * 4 + r))] * 1.4426950408889634f;  // log2e

            float4v O = czero;
            #pragma unroll
            for (int mm = 0; mm < 2; ++mm) {
                int m = mg * 2 + mm;
                const unsigned short* kk = KSH + mm * 4096;
                const unsigned short* vv = VSH + mm * 4096;
                int eim = abs(i - m);
                #pragma unroll
                for (int np = 0; np < 8; ++np) {
                    union { unsigned u[4]; short8 s8; } a2u;
                    #pragma unroll
                    for (int s = 0; s < 2; ++s) {
                        int n = np * 2 + s;
                        short8 a1 = zero8;
                        if (quad < 2)
                            a1 = *(const short8*)(kk + n * 256 + l15 * 16 + quad * 8);
                        float4v d1 = __builtin_amdgcn_mfma_f32_16x16x32_bf16(a1, qf, czero, 0, 0, 0);
                        float smn = gp[eim + abs(j - n)];        // wave-uniform
                        float e0 = __builtin_amdgcn_exp2f(d1[0] * smn * wd[0]);
                        float e1 = __builtin_amdgcn_exp2f(d1[1] * smn * wd[1]);
                        float e2 = __builtin_amdgcn_exp2f(d1[2] * smn * wd[2]);
                        float e3 = __builtin_amdgcn_exp2f(d1[3] * smn * wd[3]);
                        float sm = e0 + e1 + e2 + e3;
                        sm += __shfl_xor(sm, 16);
                        sm += __shfl_xor(sm, 32);
                        float inv = __builtin_amdgcn_rcpf(sm);
                        union { float f; unsigned u; } p0, p1, p2, p3;
                        p0.f = e0 * inv; p1.f = e1 * inv;
                        p2.f = e2 * inv; p3.f = e3 * inv;
                        a2u.u[s * 2]     = ((p0.u + 0x8000u) >> 16) | ((p1.u + 0x8000u) & 0xFFFF0000u);
                        a2u.u[s * 2 + 1] = ((p2.u + 0x8000u) >> 16) | ((p3.u + 0x8000u) & 0xFFFF0000u);
                    }
                    short8 b2 = *(const short8*)(vv + np * 512 + l15 * 32 + quad * 8);
                    O = __builtin_amdgcn_mfma_f32_16x16x32_bf16(a2u.s8, b2, O, 0, 0, 0);
                }
            }

            float* aop = aoall + mg * CN;
            float4 ov = {O[0], O[1], O[2], O[3]};
            *(float4*)(aop + (head * 16 + l15) * 4096 + t * 16 + quad * 4) = ov;
        }
    }
    grid_bar(bar, 2048);

    // ---- S4: projection (was proj_mfma_kernel, 256 blocks x 256) ----
    if (blockIdx.x < 256) {
        unsigned short* Bt = (unsigned short*)lds_raw;      // [16][PTP]
        int d   = blockIdx.x >> 4;
        int p16 = blockIdx.x & 15;
        int tid = threadIdx.x;
        bool act = tid < 256;

        if (act) {   // stage: sum 8 partials -> bf16 Bt[px][ci]
            int px = tid & 15, cig = (tid >> 4) & 15;
            int gbase = d * 256 + p16 * 16 + px;
            #pragma unroll
            for (int cc = 0; cc < 4; ++cc) {
                int ci = cig * 4 + cc;
                int ga = ci * 4096 + gbase;
                float v = 0.f;
                #pragma unroll
                for (int k = 0; k < 8; ++k) v += aoall[k * CN + ga];
                Bt[px * PTP + ci] = f2bf(v);
            }
        }
        __syncthreads();

        if (act) {
            int wv = (tid >> 6) & 3, lane = tid & 63;
            int quad = lane >> 4, l15 = lane & 15;
            float4v czero = {0.f, 0.f, 0.f, 0.f};
            float4v acc = czero;

            short8 af[2];
            const float* wsrc = w_proj + (wv * 16 + l15) * 64 + quad * 8;
            #pragma unroll
            for (int ks = 0; ks < 2; ++ks) {
                float4 wa = *(const float4*)(wsrc + ks * 32);
                float4 wb = *(const float4*)(wsrc + ks * 32 + 4);
                short8 a8 = {(short)f2bf(wa.x), (short)f2bf(wa.y), (short)f2bf(wa.z),
                             (short)f2bf(wa.w), (short)f2bf(wb.x), (short)f2bf(wb.y),
                             (short)f2bf(wb.z), (short)f2bf(wb.w)};
                af[ks] = a8;
            }
            const unsigned short* brow = Bt + l15 * PTP + quad * 8;
            #pragma unroll
            for (int ks = 0; ks < 2; ++ks) {
                short4v lo = *(const short4v*)(brow + ks * 32);
                short4v hi = *(const short4v*)(brow + ks * 32 + 4);
                short8 bf8 = {lo[0], lo[1], lo[2], lo[3], hi[0], hi[1], hi[2], hi[3]};
                acc = __builtin_amdgcn_mfma_f32_16x16x32_bf16(af[ks], bf8, acc, 0, 0, 0);
            }

            int p = d * 256 + p16 * 16 + l15;
            #pragma unroll
            for (int r = 0; r < 4; ++r) {
                int oc = wv * 16 + quad * 4 + r;
                out[oc * 4096 + p] = acc[r] + b_proj[oc];
            }
        }
    }
}

// ---------------------------------------------------------------------------
extern "C" void kernel_launch(void* const* d_in, const int* in_sizes, int n_in,
                              void* d_out, int out_size, void* d_ws, size_t ws_size,
                              hipStream_t stream) {
    const float* x      = (const float*)d_in[0];
    const float* gamma  = (const float*)d_in[1];
    const float* w_sp   = (const float*)d_in[2];
    const float* b_sp   = (const float*)d_in[3];
    const float* w_spec = (const float*)d_in[4];
    const float* b_spec = (const float*)d_in[5];
    const float* w_qkv  = (const float*)d_in[6];
    const float* b_qkv  = (const float*)d_in[7];
    const float* w_proj = (const float*)d_in[8];
    const float* b_proj = (const float*)d_in[9];
    float* out = (float*)d_out;
    float* ws = (float*)d_ws;

    // barrier counter well past all workspace tensors (they end at 11.5*CN floats)
    int* bar = (int*)(ws + 12 * CN);
    hipMemsetAsync(bar, 0, 256, stream);     // capture-legal; re-zeroed every replay

    mega_kernel<<<dim3(512), dim3(512), 0, stream>>>(
        x, gamma, w_sp, b_sp, w_spec, b_spec, w_qkv, b_qkv, w_proj, b_proj,
        out, ws, bar);
}

// Round 2
// 194.447 us; speedup vs baseline: 1.5001x; 1.5001x over previous
//
#include <hip/hip_runtime.h>
#include <math.h>

// Problem constants: B=1, C=64, D=H=W=16, HEADS=4, HD=16
#define CN   262144        // C * 4096 floats per [C, D, H, W] tensor
#define BTP 196            // qkv/conv Bt row stride in bf16
#define PTP 68             // proj Bt row stride in bf16

typedef __attribute__((ext_vector_type(8))) short short8;   // 8 bf16 (4 VGPRs)
typedef __attribute__((ext_vector_type(4))) short short4v;  // 8 B
typedef __attribute__((ext_vector_type(4))) float float4v;  // MFMA C/D

static __device__ __forceinline__ unsigned short f2bf(float f) {
    union { float f; unsigned u; } v; v.f = f;
    unsigned r = (v.u + 0x7FFFu + ((v.u >> 16) & 1u)) >> 16;   // RNE
    return (unsigned short)r;
}

// ---------------------------------------------------------------------------
// Contention-free grid barrier (v2).
// R1 post-mortem: single-counter atomicAdd barrier cost ~48us/barrier (512
// same-address device-scope RMWs serialize ~90ns each). v2 removes ALL
// same-address RMWs:
//   - each block stores phase to its OWN arrive flag (512 independent stores)
//   - block 0 wave 0 polls all 512 flags (8/lane, independent loads)
//   - block 0 thread 0 publishes one release word; others poll it (plain
//     loads to one line, no RMW serialization)
// Monotonic phase numbers; flags zeroed by hipMemsetAsync each graph replay.
// Co-residency of all 512 blocks guaranteed by __launch_bounds__(512,4)
// (44 VGPR, 33 KB LDS -> 2 blocks/CU x 256 CU). Bounded spin as fail-safe:
// a bug degrades to a wrong answer, not a hang.
#define BAR_LIMIT (1 << 20)

static __device__ __forceinline__ void grid_bar(int* arrive, int* release, int phase) {
    __syncthreads();                         // whole block arrived
    if (blockIdx.x == 0) {
        if (threadIdx.x < 64) {              // master wave
            if (threadIdx.x == 0) {
                __threadfence();             // publish block 0's stage writes
                __hip_atomic_store(&arrive[0], phase,
                                   __ATOMIC_RELAXED, __HIP_MEMORY_SCOPE_AGENT);
            }
            int base = threadIdx.x * 8;      // 8 flags per lane -> 512 total
            int z = 0;
            bool done = false;
            while (!done && z < BAR_LIMIT) {
                int mn = phase;
                #pragma unroll
                for (int q = 0; q < 8; ++q) {
                    int a = __hip_atomic_load(&arrive[base + q],
                                              __ATOMIC_RELAXED, __HIP_MEMORY_SCOPE_AGENT);
                    mn = (a < mn) ? a : mn;
                }
                done = (mn >= phase);
                ++z;
            }
        }
        __syncthreads();                     // poll done across master wave
        if (threadIdx.x == 0) {
            __threadfence();                 // order: saw arrivals -> release
            __hip_atomic_store(release, phase,
                               __ATOMIC_RELAXED, __HIP_MEMORY_SCOPE_AGENT);
            __threadfence();                 // acquire for block 0's own reads
        }
        __syncthreads();
    } else {
        if (threadIdx.x == 0) {
            __threadfence();                 // publish this block's stage writes
            __hip_atomic_store(&arrive[blockIdx.x], phase,
                               __ATOMIC_RELAXED, __HIP_MEMORY_SCOPE_AGENT);
            int z = 0;
            while (__hip_atomic_load(release, __ATOMIC_RELAXED,
                                     __HIP_MEMORY_SCOPE_AGENT) < phase
                   && z < BAR_LIMIT) {
                __builtin_amdgcn_s_sleep(1);
                ++z;
            }
            __threadfence();                 // acquire (L1/L2 invalidate)
        }
        __syncthreads();
    }
}

// ---------------------------------------------------------------------------
// Mega-kernel: all 5 pipeline stages, separated by grid barriers instead of
// kernel boundaries. Stage bodies are bit-identical to the 5-kernel version
// (r16-verified numerics preserved).
// Grid 512 x 512 threads; LDS union = max(stage LDS) = 32.9 KB.
__global__ __launch_bounds__(512, 4) void mega_kernel(
        const float* __restrict__ x, const float* __restrict__ gamma,
        const float* __restrict__ w_sp, const float* __restrict__ b_sp,
        const float* __restrict__ w_spec, const float* __restrict__ b_spec,
        const float* __restrict__ w_qkv, const float* __restrict__ b_qkv,
        const float* __restrict__ w_proj, const float* __restrict__ b_proj,
        float* __restrict__ out, float* ws, int* arrive, int* release) {
    // LDS union: conv Bt 6.3KB | qkv Bt 12.5KB | attn ksh16K+vsh16K+gp128 | proj 2.2KB
    __shared__ __align__(16) unsigned char lds_raw[32896];

    float* y1  = ws;                                        // [64][4096] f32
    unsigned short* wfb = (unsigned short*)(ws + CN);       // [192][192] bf16
    float* bfv = ws + CN + 20480;                           // [192] fused bias f32
    unsigned short* wsb = (unsigned short*)(ws + CN + 24576); // [3][64][192] bf16
    unsigned short* qb  = (unsigned short*)(ws + 2 * CN);
    unsigned short* kb  = (unsigned short*)(ws + 2 * CN + CN / 2);
    unsigned short* vtb = (unsigned short*)(ws + 3 * CN);
    float* aoall = ws + 3 * CN + CN / 2;                    // 8 x [64][4096]

    // ---- S0: weight prep (was wprep_kernel, 144x512 = 73728 items) ----
    {
        int idx = blockIdx.x * 512 + threadIdx.x;           // 0..262143
        if (idx < 36864) {
            int dh  = idx / 12288;
            int rem = idx % 12288;
            int co  = rem / 192;
            int kp  = rem % 192;                            // = ci*3 + dw
            int ci = kp / 3, dw = kp % 3;
            wsb[idx] = f2bf(w_sp[co * 576 + ci * 9 + dh * 3 + dw]);
        } else if (idx < 73728) {
            int j = idx - 36864;                            // 0..36863
            int oc = j / 192;
            int r  = j % 192;                               // = cj*3 + t
            float s = 0.f;
            #pragma unroll 8
            for (int ci = 0; ci < 64; ++ci)
                s += w_qkv[oc * 64 + ci] * w_spec[ci * 192 + r];
            if (oc < 64) s *= 0.25f;
            wfb[oc * 192 + r] = f2bf(s);
            if (j < 192) {
                float t = b_qkv[j];
                for (int ci = 0; ci < 64; ++ci) t += w_qkv[j * 64 + ci] * b_spec[ci];
                if (j < 64) t *= 0.25f;
                bfv[j] = t;
            }
        }
    }
    grid_bar(arrive, release, 1);

    // ---- S1: spatial conv 3x3 (was conv_sp_mfma_kernel, 256 blocks x 256) ----
    if (blockIdx.x < 256) {
        unsigned short* Bt = (unsigned short*)lds_raw;      // [16][BTP]
        int d = blockIdx.x >> 4;
        int h = blockIdx.x & 15;
        int tid = threadIdx.x;
        bool act = tid < 256;                               // waves 0-3 active
        int px = tid & 15, cig = (tid >> 4) & 15;

        float rcur[12], rnxt[12];
        #define LOAD_CHUNK(dh_, rr)                                            \
            {                                                                  \
                int hh = h + (dh_) - 1;                                        \
                _Pragma("unroll")                                              \
                for (int cc = 0; cc < 4; ++cc) {                               \
                    int ci = cig * 4 + cc;                                     \
                    const float* xr = x + ci * 4096 + d * 256 + hh * 16;       \
                    _Pragma("unroll")                                          \
                    for (int dw = 0; dw < 3; ++dw) {                           \
                        int ww = px + dw - 1;                                  \
                        float v = 0.f;                                         \
                        if (hh >= 0 && hh <= 15 && ww >= 0 && ww <= 15)        \
                            v = xr[ww];                                        \
                        (rr)[cc * 3 + dw] = v;                                 \
                    }                                                          \
                }                                                              \
            }

        if (act) LOAD_CHUNK(0, rcur);

        int wv = (tid >> 6) & 3, lane = tid & 63;
        int quad = lane >> 4, l15 = lane & 15;
        float4v acc = {0.f, 0.f, 0.f, 0.f};

        #pragma unroll
        for (int c = 0; c < 3; ++c) {
            __syncthreads();                 // guard Bt reuse across chunks
            if (act) {
                #pragma unroll
                for (int cc = 0; cc < 4; ++cc) {
                    int ci = cig * 4 + cc;
                    Bt[px * BTP + ci * 3 + 0] = f2bf(rcur[cc * 3 + 0]);
                    Bt[px * BTP + ci * 3 + 1] = f2bf(rcur[cc * 3 + 1]);
                    Bt[px * BTP + ci * 3 + 2] = f2bf(rcur[cc * 3 + 2]);
                }
            }
            __syncthreads();
            if (act) {
                if (c < 2) LOAD_CHUNK(c + 1, rnxt);

                const unsigned short* ab = wsb + c * 12288 + (wv * 16 + l15) * 192 + quad * 8;
                const unsigned short* brow = Bt + l15 * BTP + quad * 8;
                #pragma unroll
                for (int ks = 0; ks < 6; ++ks) {
                    short8 af = *(const short8*)(ab + ks * 32);
                    short4v lo = *(const short4v*)(brow + ks * 32);
                    short4v hi = *(const short4v*)(brow + ks * 32 + 4);
                    short8 bf8 = {lo[0], lo[1], lo[2], lo[3], hi[0], hi[1], hi[2], hi[3]};
                    acc = __builtin_amdgcn_mfma_f32_16x16x32_bf16(af, bf8, acc, 0, 0, 0);
                }
                #pragma unroll
                for (int q2 = 0; q2 < 12; ++q2) rcur[q2] = rnxt[q2];
            }
        }

        if (act) {
            int p = d * 256 + h * 16 + l15;
            #pragma unroll
            for (int r = 0; r < 4; ++r) {
                int co = wv * 16 + quad * 4 + r;
                y1[co * 4096 + p] = acc[r] + b_sp[co];
            }
        }
        #undef LOAD_CHUNK
    }
    grid_bar(arrive, release, 2);

    // ---- S2: spectral-conv + QKV (was qkv_mfma_kernel, 384 blocks x 512) ----
    if (blockIdx.x < 384) {
        unsigned short* Bt = (unsigned short*)lds_raw;      // [32][BTP]
        int bI  = blockIdx.x;            // 384 = 16 d x 8 pq x 3 ocg
        int ocg = bI % 3;                // 0=q 1=k 2=v
        int pq  = (bI / 3) & 7;
        int d   = bI / 24;
        int tid = threadIdx.x;

        {   // stage im2col slab: Bt[px][ci*3+t] = y1[ci][d+t-1][pq*32+px]
            int px  = tid & 31;
            int cig = tid >> 5;          // 0..15 (4 ci each)
            const float* yb = y1 + d * 256 + pq * 32 + px;
            #pragma unroll
            for (int cc = 0; cc < 4; ++cc) {
                int ci = cig * 4 + cc;
                const float* yc = yb + ci * 4096;
                #pragma unroll
                for (int t = 0; t < 3; ++t) {
                    float v = 0.f;
                    if (!((d == 0 && t == 0) || (d == 15 && t == 2)))
                        v = yc[(t - 1) * 256];
                    Bt[px * BTP + ci * 3 + t] = f2bf(v);
                }
            }
        }

        int wv = tid >> 6, lane = tid & 63;
        int quad = lane >> 4, l15 = lane & 15;
        int Mt = wv >> 1;                // 0..3 (= head)
        int nt = wv & 1;                 // N-tile (16 pos)

        short8 af[6];
        {
            const unsigned short* ab = wfb + (ocg * 64 + Mt * 16 + l15) * 192 + quad * 8;
            #pragma unroll
            for (int ks = 0; ks < 6; ++ks) af[ks] = *(const short8*)(ab + ks * 32);
        }
        float bias[4];
        #pragma unroll
        for (int r = 0; r < 4; ++r) bias[r] = bfv[ocg * 64 + Mt * 16 + quad * 4 + r];

        __syncthreads();

        float4v czero = {0.f, 0.f, 0.f, 0.f};
        float4v acc = czero;
        {
            const unsigned short* brow = Bt + (nt * 16 + l15) * BTP + quad * 8;
            #pragma unroll
            for (int ks = 0; ks < 6; ++ks) {
                short4v lo = *(const short4v*)(brow + ks * 32);
                short4v hi = *(const short4v*)(brow + ks * 32 + 4);
                short8 bf8 = {lo[0], lo[1], lo[2], lo[3], hi[0], hi[1], hi[2], hi[3]};
                acc = __builtin_amdgcn_mfma_f32_16x16x32_bf16(af[ks], bf8, acc, 0, 0, 0);
            }
        }

        {   // epilogue: C row = oc_local (quad*4+r), col = pos (l15)
            int p = d * 256 + pq * 32 + nt * 16 + l15;
            if (ocg == 2) {
                int h = (p >> 4) & 15, w0 = p & 15;
                int kap = 8 * (w0 >> 2) + 4 * (h & 1) + (w0 & 3);
                unsigned short* dst = vtb + ((Mt * 16 + d) * 8 + (h >> 1)) * 512
                                          + (quad * 4) * 32 + kap;
                #pragma unroll
                for (int r = 0; r < 4; ++r) dst[r * 32] = f2bf(acc[r] + bias[r]);
            } else {
                unsigned short* dst = (ocg == 0 ? qb : kb) + Mt * 65536 + p * 16 + quad * 4;
                unsigned t0 = (unsigned)f2bf(acc[0] + bias[0])
                            | ((unsigned)f2bf(acc[1] + bias[1]) << 16);
                unsigned t1 = (unsigned)f2bf(acc[2] + bias[2])
                            | ((unsigned)f2bf(acc[3] + bias[3]) << 16);
                *(unsigned*)dst = t0;
                *(unsigned*)(dst + 2) = t1;
            }
        }
    }
    grid_bar(arrive, release, 3);

    // ---- S3: retention attention (was attn_kernel, 1024 blocks x 512) ----
    // Each physical block runs 2 virtual blocks sequentially.
    {
        unsigned short* KSH = (unsigned short*)lds_raw;          // [2][4096]
        unsigned short* VSH = (unsigned short*)lds_raw + 8192;   // [2][4096]
        float* gp = (float*)(lds_raw + 32768);                   // [32]
        int tid = threadIdx.x;
        if (tid < 32) {
            float g = 1.f / (1.f + __expf(-gamma[0]));
            gp[tid] = __powf(g, (float)tid);
        }
        int wv = tid >> 6, lane = tid & 63;
        int quad = lane >> 4, l15 = lane & 15;
        short8 zero8 = {0, 0, 0, 0, 0, 0, 0, 0};
        float4v czero = {0.f, 0.f, 0.f, 0.f};

        #pragma unroll 1
        for (int it = 0; it < 2; ++it) {
            int bI = blockIdx.x + it * 512;    // virtual block 0..1023
            int head = bI >> 8;
            int mg   = (bI >> 5) & 7;
            int oct  = bI & 31;
            int t = oct * 8 + wv;
            int i = t >> 4, j = t & 15;

            short8 qf = zero8;
            if (quad < 2)
                qf = *(const short8*)(qb + head * 65536 + (t * 16 + l15) * 16 + quad * 8);

            const unsigned short* kbh = kb  + head * 65536 + mg * 2 * 4096;
            const unsigned short* vbh = vtb + head * 65536 + mg * 2 * 4096;
            float4 k0 = ((const float4*)kbh)[tid];
            float4 v0 = ((const float4*)vbh)[tid];
            float4 k1 = ((const float4*)(kbh + 4096))[tid];
            float4 v1 = ((const float4*)(vbh + 4096))[tid];
            __syncthreads();                   // prev-iter LDS readers done
            ((float4*)KSH)[tid] = k0;
            ((float4*)VSH)[tid] = v0;
            ((float4*)(KSH + 4096))[tid] = k1;
            ((float4*)(VSH + 4096))[tid] = v1;
            __syncthreads();                   // gp + both slabs ready

            float wd[4];
            #pragma unroll
            for (int r = 0; r < 4; ++r)
                wd[r] = gp[abs(l15 - (quad * 4 + r))] * 1.4426950408889634f;  // log2e

            float4v O = czero;
            #pragma unroll
            for (int mm = 0; mm < 2; ++mm) {
                int m = mg * 2 + mm;
                const unsigned short* kk = KSH + mm * 4096;
                const unsigned short* vv = VSH + mm * 4096;
                int eim = abs(i - m);
                #pragma unroll
                for (int np = 0; np < 8; ++np) {
                    union { unsigned u[4]; short8 s8; } a2u;
                    #pragma unroll
                    for (int s = 0; s < 2; ++s) {
                        int n = np * 2 + s;
                        short8 a1 = zero8;
                        if (quad < 2)
                            a1 = *(const short8*)(kk + n * 256 + l15 * 16 + quad * 8);
                        float4v d1 = __builtin_amdgcn_mfma_f32_16x16x32_bf16(a1, qf, czero, 0, 0, 0);
                        float smn = gp[eim + abs(j - n)];        // wave-uniform
                        float e0 = __builtin_amdgcn_exp2f(d1[0] * smn * wd[0]);
                        float e1 = __builtin_amdgcn_exp2f(d1[1] * smn * wd[1]);
                        float e2 = __builtin_amdgcn_exp2f(d1[2] * smn * wd[2]);
                        float e3 = __builtin_amdgcn_exp2f(d1[3] * smn * wd[3]);
                        float sm = e0 + e1 + e2 + e3;
                        sm += __shfl_xor(sm, 16);
                        sm += __shfl_xor(sm, 32);
                        float inv = __builtin_amdgcn_rcpf(sm);
                        union { float f; unsigned u; } p0, p1, p2, p3;
                        p0.f = e0 * inv; p1.f = e1 * inv;
                        p2.f = e2 * inv; p3.f = e3 * inv;
                        a2u.u[s * 2]     = ((p0.u + 0x8000u) >> 16) | ((p1.u + 0x8000u) & 0xFFFF0000u);
                        a2u.u[s * 2 + 1] = ((p2.u + 0x8000u) >> 16) | ((p3.u + 0x8000u) & 0xFFFF0000u);
                    }
                    short8 b2 = *(const short8*)(vv + np * 512 + l15 * 32 + quad * 8);
                    O = __builtin_amdgcn_mfma_f32_16x16x32_bf16(a2u.s8, b2, O, 0, 0, 0);
                }
            }

            float* aop = aoall + mg * CN;
            float4 ov = {O[0], O[1], O[2], O[3]};
            *(float4*)(aop + (head * 16 + l15) * 4096 + t * 16 + quad * 4) = ov;
        }
    }
    grid_bar(arrive, release, 4);

    // ---- S4: projection (was proj_mfma_kernel, 256 blocks x 256) ----
    if (blockIdx.x < 256) {
        unsigned short* Bt = (unsigned short*)lds_raw;      // [16][PTP]
        int d   = blockIdx.x >> 4;
        int p16 = blockIdx.x & 15;
        int tid = threadIdx.x;
        bool act = tid < 256;

        if (act) {   // stage: sum 8 partials -> bf16 Bt[px][ci]
            int px = tid & 15, cig = (tid >> 4) & 15;
            int gbase = d * 256 + p16 * 16 + px;
            #pragma unroll
            for (int cc = 0; cc < 4; ++cc) {
                int ci = cig * 4 + cc;
                int ga = ci * 4096 + gbase;
                float v = 0.f;
                #pragma unroll
                for (int k = 0; k < 8; ++k) v += aoall[k * CN + ga];
                Bt[px * PTP + ci] = f2bf(v);
            }
        }
        __syncthreads();

        if (act) {
            int wv = (tid >> 6) & 3, lane = tid & 63;
            int quad = lane >> 4, l15 = lane & 15;
            float4v czero = {0.f, 0.f, 0.f, 0.f};
            float4v acc = czero;

            short8 af[2];
            const float* wsrc = w_proj + (wv * 16 + l15) * 64 + quad * 8;
            #pragma unroll
            for (int ks = 0; ks < 2; ++ks) {
                float4 wa = *(const float4*)(wsrc + ks * 32);
                float4 wb = *(const float4*)(wsrc + ks * 32 + 4);
                short8 a8 = {(short)f2bf(wa.x), (short)f2bf(wa.y), (short)f2bf(wa.z),
                             (short)f2bf(wa.w), (short)f2bf(wb.x), (short)f2bf(wb.y),
                             (short)f2bf(wb.z), (short)f2bf(wb.w)};
                af[ks] = a8;
            }
            const unsigned short* brow = Bt + l15 * PTP + quad * 8;
            #pragma unroll
            for (int ks = 0; ks < 2; ++ks) {
                short4v lo = *(const short4v*)(brow + ks * 32);
                short4v hi = *(const short4v*)(brow + ks * 32 + 4);
                short8 bf8 = {lo[0], lo[1], lo[2], lo[3], hi[0], hi[1], hi[2], hi[3]};
                acc = __builtin_amdgcn_mfma_f32_16x16x32_bf16(af[ks], bf8, acc, 0, 0, 0);
            }

            int p = d * 256 + p16 * 16 + l15;
            #pragma unroll
            for (int r = 0; r < 4; ++r) {
                int oc = wv * 16 + quad * 4 + r;
                out[oc * 4096 + p] = acc[r] + b_proj[oc];
            }
        }
    }
}

// ---------------------------------------------------------------------------
extern "C" void kernel_launch(void* const* d_in, const int* in_sizes, int n_in,
                              void* d_out, int out_size, void* d_ws, size_t ws_size,
                              hipStream_t stream) {
    const float* x      = (const float*)d_in[0];
    const float* gamma  = (const float*)d_in[1];
    const float* w_sp   = (const float*)d_in[2];
    const float* b_sp   = (const float*)d_in[3];
    const float* w_spec = (const float*)d_in[4];
    const float* b_spec = (const float*)d_in[5];
    const float* w_qkv  = (const float*)d_in[6];
    const float* b_qkv  = (const float*)d_in[7];
    const float* w_proj = (const float*)d_in[8];
    const float* b_proj = (const float*)d_in[9];
    float* out = (float*)d_out;
    float* ws = (float*)d_ws;

    // barrier flags past all workspace tensors (they end at 11.5*CN floats):
    // arrive[512] ints, release on its own cacheline at +768 ints.
    int* arrive  = (int*)(ws + 12 * CN);
    int* release = arrive + 768;
    hipMemsetAsync(arrive, 0, 4096, stream);   // capture-legal; re-zeroed every replay

    mega_kernel<<<dim3(512), dim3(512), 0, stream>>>(
        x, gamma, w_sp, b_sp, w_spec, b_spec, w_qkv, b_qkv, w_proj, b_proj,
        out, ws, arrive, release);
}

// Round 3
// 146.113 us; speedup vs baseline: 1.9963x; 1.3308x over previous
//
#include <hip/hip_runtime.h>
#include <math.h>

// Problem constants: B=1, C=64, D=H=W=16, HEADS=4, HD=16
#define CN   262144        // C * 4096 floats per [C, D, H, W] tensor
#define BTP 196            // qkv/conv Bt row stride in bf16
#define PTP 68             // proj Bt row stride in bf16

typedef __attribute__((ext_vector_type(8))) short short8;   // 8 bf16 (4 VGPRs)
typedef __attribute__((ext_vector_type(4))) short short4v;  // 8 B
typedef __attribute__((ext_vector_type(4))) float float4v;  // MFMA C/D

static __device__ __forceinline__ unsigned short f2bf(float f) {
    union { float f; unsigned u; } v; v.f = f;
    unsigned r = (v.u + 0x7FFFu + ((v.u >> 16) & 1u)) >> 16;   // RNE
    return (unsigned short)r;
}

// ---------------------------------------------------------------------------
// L2-bypass (device-coherent) scalar accesses for ALL inter-stage tensors.
// These compile to global_load/store_dword sc1: serviced at the device
// coherence point, so no dirty per-XCD L2 state is ever created for
// cross-stage data => grid barriers need NO cache maintenance (no
// buffer_wbl2 / buffer_inv), which R2 evidence says was the ~24us/barrier.
// __syncthreads() drains vmcnt (store acks) before s_barrier, giving the
// release ordering for free.
static __device__ __forceinline__ unsigned ld_u32g(const void* p) {
    return __hip_atomic_load((const unsigned*)p, __ATOMIC_RELAXED,
                             __HIP_MEMORY_SCOPE_AGENT);
}
static __device__ __forceinline__ void st_u32g(void* p, unsigned v) {
    __hip_atomic_store((unsigned*)p, v, __ATOMIC_RELAXED,
                       __HIP_MEMORY_SCOPE_AGENT);
}
static __device__ __forceinline__ float ld_f32g(const void* p) {
    return __hip_atomic_load((const float*)p, __ATOMIC_RELAXED,
                             __HIP_MEMORY_SCOPE_AGENT);
}
static __device__ __forceinline__ void st_f32g(void* p, float v) {
    __hip_atomic_store((float*)p, v, __ATOMIC_RELAXED,
                       __HIP_MEMORY_SCOPE_AGENT);
}

// ---------------------------------------------------------------------------
// Grid barrier v3: fence-free (see above), contention-free.
//   - arrive flags padded to 128B lines (independent stores, no RMW)
//   - block 0 wave 0 polls 8 flags/lane; divergent-loop reconvergence =>
//     all 512 seen; then each lane stores one of 64 release replicas
//   - waiter b polls replica (b & 63): <=8 pollers per line
// Monotonic phases; flags zeroed by hipMemsetAsync each replay.
// Co-residency: __launch_bounds__(512,4) => 2 blocks/CU x 256 CU = 512.
// Bounded spin: a bug degrades to a wrong answer, not a hang.
#define BAR_LIMIT (1 << 20)

static __device__ __forceinline__ void grid_bar(int* arrive, int* release, int phase) {
    __syncthreads();                       // all block threads arrived; vmcnt drained
    if (blockIdx.x == 0) {
        if (threadIdx.x < 64) {            // master wave
            if (threadIdx.x == 0)
                __hip_atomic_store(&arrive[0], phase,
                                   __ATOMIC_RELAXED, __HIP_MEMORY_SCOPE_AGENT);
            int base = (int)threadIdx.x * 8 * 32;   // 8 padded flags per lane
            int z = 0; bool done = false;
            while (!done && z < BAR_LIMIT) {
                int mn = phase;
                #pragma unroll
                for (int q = 0; q < 8; ++q) {
                    int a = __hip_atomic_load(&arrive[base + q * 32],
                                              __ATOMIC_RELAXED, __HIP_MEMORY_SCOPE_AGENT);
                    mn = (a < mn) ? a : mn;
                }
                done = (mn >= phase);
                if (!done) __builtin_amdgcn_s_sleep(1);
                ++z;
            }
            // reconvergence: all 64 lanes saw their 8 flags => all 512 done
            __hip_atomic_store(&release[(int)threadIdx.x * 32], phase,
                               __ATOMIC_RELAXED, __HIP_MEMORY_SCOPE_AGENT);
        }
        __syncthreads();
    } else {
        if (threadIdx.x == 0) {
            __hip_atomic_store(&arrive[(int)blockIdx.x * 32], phase,
                               __ATOMIC_RELAXED, __HIP_MEMORY_SCOPE_AGENT);
            int* rel = &release[(blockIdx.x & 63) * 32];
            int z = 0;
            while (__hip_atomic_load(rel, __ATOMIC_RELAXED,
                                     __HIP_MEMORY_SCOPE_AGENT) < phase
                   && z < BAR_LIMIT) {
                __builtin_amdgcn_s_sleep(8);
                ++z;
            }
        }
        __syncthreads();
    }
}

// ---------------------------------------------------------------------------
// Mega-kernel v3: 4 phases, 3 grid barriers.
//  A: conv_sp (blocks 0-255, inline w_sp->bf16 fragments)  ||  wfb/bfv fusion
//     prep (blocks 256-511, previously a separate stage+barrier)
//  B: spectral+QKV GEMM   C: retention attention (x2 virtual)   D: projection
// All inter-stage tensors via sc1 (L2-bypass) scalar atomics; numerics are
// bit-identical to the r16-verified 5-kernel pipeline.
__global__ __launch_bounds__(512, 4) void mega_kernel(
        const float* __restrict__ x, const float* __restrict__ gamma,
        const float* __restrict__ w_sp, const float* __restrict__ b_sp,
        const float* __restrict__ w_spec, const float* __restrict__ b_spec,
        const float* __restrict__ w_qkv, const float* __restrict__ b_qkv,
        const float* __restrict__ w_proj, const float* __restrict__ b_proj,
        float* __restrict__ out, float* ws, int* arrive, int* release) {
    // LDS union: conv Bt 6.3KB | qkv Bt 12.5KB | attn ksh16K+vsh16K+gp128 | proj 2.2KB
    __shared__ __align__(16) unsigned char lds_raw[32896];

    float* y1  = ws;                                        // [64][4096] f32
    unsigned short* wfb = (unsigned short*)(ws + CN);       // [192][192] bf16
    float* bfv = ws + CN + 20480;                           // [192] fused bias f32
    unsigned short* qb  = (unsigned short*)(ws + 2 * CN);
    unsigned short* kb  = (unsigned short*)(ws + 2 * CN + CN / 2);
    unsigned short* vtb = (unsigned short*)(ws + 3 * CN);
    float* aoall = ws + 3 * CN + CN / 2;                    // 8 x [64][4096]

    // ================= Phase A =================
    if (blockIdx.x < 256) {
        // ---- spatial conv 3x3, A-fragments converted inline from w_sp ----
        unsigned short* Bt = (unsigned short*)lds_raw;      // [16][BTP]
        int d = blockIdx.x >> 4;
        int h = blockIdx.x & 15;
        int tid = threadIdx.x;
        bool act = tid < 256;                               // waves 0-3 active
        int px = tid & 15, cig = (tid >> 4) & 15;

        float rcur[12], rnxt[12];
        #define LOAD_CHUNK(dh_, rr)                                            \
            {                                                                  \
                int hh = h + (dh_) - 1;                                        \
                _Pragma("unroll")                                              \
                for (int cc = 0; cc < 4; ++cc) {                               \
                    int ci = cig * 4 + cc;                                     \
                    const float* xr = x + ci * 4096 + d * 256 + hh * 16;       \
                    _Pragma("unroll")                                          \
                    for (int dw = 0; dw < 3; ++dw) {                           \
                        int ww = px + dw - 1;                                  \
                        float v = 0.f;                                         \
                        if (hh >= 0 && hh <= 15 && ww >= 0 && ww <= 15)        \
                            v = xr[ww];                                        \
                        (rr)[cc * 3 + dw] = v;                                 \
                    }                                                          \
                }                                                              \
            }

        if (act) LOAD_CHUNK(0, rcur);

        int wv = (tid >> 6) & 3, lane = tid & 63;
        int quad = lane >> 4, l15 = lane & 15;
        float4v acc = {0.f, 0.f, 0.f, 0.f};
        // row of w_sp for this lane's co; element kp -> +c*3 + (kp/3)*9 + kp%3
        const float* wrow = w_sp + (wv * 16 + l15) * 576;

        #pragma unroll
        for (int c = 0; c < 3; ++c) {
            __syncthreads();                 // guard Bt reuse across chunks
            if (act) {
                #pragma unroll
                for (int cc = 0; cc < 4; ++cc) {
                    int ci = cig * 4 + cc;
                    Bt[px * BTP + ci * 3 + 0] = f2bf(rcur[cc * 3 + 0]);
                    Bt[px * BTP + ci * 3 + 1] = f2bf(rcur[cc * 3 + 1]);
                    Bt[px * BTP + ci * 3 + 2] = f2bf(rcur[cc * 3 + 2]);
                }
            }
            __syncthreads();
            if (act) {
                if (c < 2) LOAD_CHUNK(c + 1, rnxt);

                const unsigned short* brow = Bt + l15 * BTP + quad * 8;
                #pragma unroll
                for (int ks = 0; ks < 6; ++ks) {
                    short8 af;
                    #pragma unroll
                    for (int j = 0; j < 8; ++j) {
                        int kp = quad * 8 + ks * 32 + j;       // c-independent ci/dw: CSE'd
                        af[j] = (short)f2bf(wrow[c * 3 + (kp / 3) * 9 + (kp % 3)]);
                    }
                    short4v lo = *(const short4v*)(brow + ks * 32);
                    short4v hi = *(const short4v*)(brow + ks * 32 + 4);
                    short8 bf8 = {lo[0], lo[1], lo[2], lo[3], hi[0], hi[1], hi[2], hi[3]};
                    acc = __builtin_amdgcn_mfma_f32_16x16x32_bf16(af, bf8, acc, 0, 0, 0);
                }
                #pragma unroll
                for (int q2 = 0; q2 < 12; ++q2) rcur[q2] = rnxt[q2];
            }
        }

        if (act) {
            int p = d * 256 + h * 16 + l15;
            #pragma unroll
            for (int r = 0; r < 4; ++r) {
                int co = wv * 16 + quad * 4 + r;
                st_f32g(y1 + co * 4096 + p, acc[r] + b_sp[co]);
            }
        }
        #undef LOAD_CHUNK
    } else {
        // ---- wfb/bfv fusion prep (runs concurrently with conv) ----
        int idx = (blockIdx.x - 256) * 512 + threadIdx.x;   // 0..131071
        if (idx < 18432) {                  // wfb as u32 pairs (2 adjacent r)
            int oc = idx / 96;
            int rp = idx % 96;
            int r0 = rp * 2;
            float s0 = 0.f, s1 = 0.f;
            #pragma unroll 8
            for (int ci = 0; ci < 64; ++ci) {
                float wq = w_qkv[oc * 64 + ci];
                s0 += wq * w_spec[ci * 192 + r0];
                s1 += wq * w_spec[ci * 192 + r0 + 1];
            }
            if (oc < 64) { s0 *= 0.25f; s1 *= 0.25f; }
            st_u32g(wfb + oc * 192 + r0,
                    (unsigned)f2bf(s0) | ((unsigned)f2bf(s1) << 16));
        } else if (idx < 18432 + 192) {
            int j = idx - 18432;
            float t = b_qkv[j];
            for (int ci = 0; ci < 64; ++ci) t += w_qkv[j * 64 + ci] * b_spec[ci];
            if (j < 64) t *= 0.25f;
            st_f32g(bfv + j, t);
        }
    }
    grid_bar(arrive, release, 1);

    // ================= Phase B: spectral-conv + QKV GEMM =================
    if (blockIdx.x < 384) {
        unsigned short* Bt = (unsigned short*)lds_raw;      // [32][BTP]
        int bI  = blockIdx.x;            // 384 = 16 d x 8 pq x 3 ocg
        int ocg = bI % 3;                // 0=q 1=k 2=v
        int pq  = (bI / 3) & 7;
        int d   = bI / 24;
        int tid = threadIdx.x;

        {   // stage im2col slab: Bt[px][ci*3+t] = y1[ci][d+t-1][pq*32+px]
            int px  = tid & 31;
            int cig = tid >> 5;          // 0..15 (4 ci each)
            const float* yb = y1 + d * 256 + pq * 32 + px;
            #pragma unroll
            for (int cc = 0; cc < 4; ++cc) {
                int ci = cig * 4 + cc;
                const float* yc = yb + ci * 4096;
                #pragma unroll
                for (int t = 0; t < 3; ++t) {
                    float v = 0.f;
                    if (!((d == 0 && t == 0) || (d == 15 && t == 2)))
                        v = ld_f32g(yc + (t - 1) * 256);
                    Bt[px * BTP + ci * 3 + t] = f2bf(v);
                }
            }
        }

        int wv = tid >> 6, lane = tid & 63;
        int quad = lane >> 4, l15 = lane & 15;
        int Mt = wv >> 1;                // 0..3 (= head)
        int nt = wv & 1;                 // N-tile (16 pos)

        short8 af[6];
        {
            const unsigned* ab = (const unsigned*)(wfb + (ocg * 64 + Mt * 16 + l15) * 192)
                                 + quad * 4;
            #pragma unroll
            for (int ks = 0; ks < 6; ++ks) {
                union { unsigned u[4]; short8 s8; } t;
                #pragma unroll
                for (int q = 0; q < 4; ++q) t.u[q] = ld_u32g(ab + ks * 16 + q);
                af[ks] = t.s8;
            }
        }
        float bias[4];
        #pragma unroll
        for (int r = 0; r < 4; ++r)
            bias[r] = ld_f32g(bfv + ocg * 64 + Mt * 16 + quad * 4 + r);

        __syncthreads();

        float4v czero = {0.f, 0.f, 0.f, 0.f};
        float4v acc = czero;
        {
            const unsigned short* brow = Bt + (nt * 16 + l15) * BTP + quad * 8;
            #pragma unroll
            for (int ks = 0; ks < 6; ++ks) {
                short4v lo = *(const short4v*)(brow + ks * 32);
                short4v hi = *(const short4v*)(brow + ks * 32 + 4);
                short8 bf8 = {lo[0], lo[1], lo[2], lo[3], hi[0], hi[1], hi[2], hi[3]};
                acc = __builtin_amdgcn_mfma_f32_16x16x32_bf16(af[ks], bf8, acc, 0, 0, 0);
            }
        }

        {   // epilogue: C row = oc_local (quad*4+r), col = pos (l15)
            int p = d * 256 + pq * 32 + nt * 16 + l15;
            if (ocg == 2) {
                // vtb: same u16 values/locations as before, gathered into u32
                // pairs via lane^1 shfl (kap(l15 even) and kap+1 are adjacent).
                int h = (p >> 4) & 15, w0 = p & 15;         // h wave-uniform, w0=l15
                int kap = 8 * (w0 >> 2) + 4 * (h & 1) + (w0 & 3);
                unsigned short* dstb = vtb + ((Mt * 16 + d) * 8 + (h >> 1)) * 512
                                           + (quad * 4) * 32;
                int odd = l15 & 1;
                int kap_e = kap - odd;                      // even kap of the pair
                #pragma unroll
                for (int r = 0; r < 4; ++r) {
                    unsigned self = f2bf(acc[r] + bias[r]);
                    unsigned other = (unsigned)__shfl_xor((int)self, 1) & 0xFFFFu;
                    unsigned pk = odd ? (other | (self << 16)) : (self | (other << 16));
                    if ((r < 2) == (odd != 0)) continue;    // even lanes r=0,1; odd r=2,3
                    st_u32g(dstb + r * 32 + kap_e, pk);
                }
            } else {
                unsigned short* dst = (ocg == 0 ? qb : kb) + Mt * 65536 + p * 16 + quad * 4;
                unsigned t0 = (unsigned)f2bf(acc[0] + bias[0])
                            | ((unsigned)f2bf(acc[1] + bias[1]) << 16);
                unsigned t1 = (unsigned)f2bf(acc[2] + bias[2])
                            | ((unsigned)f2bf(acc[3] + bias[3]) << 16);
                st_u32g(dst, t0);
                st_u32g(dst + 2, t1);
            }
        }
    }
    grid_bar(arrive, release, 2);

    // ================= Phase C: retention attention (x2 virtual) =================
    {
        unsigned short* KSH = (unsigned short*)lds_raw;          // [2][4096]
        unsigned short* VSH = (unsigned short*)lds_raw + 8192;   // [2][4096]
        float* gp = (float*)(lds_raw + 32768);                   // [32]
        int tid = threadIdx.x;
        if (tid < 32) {
            float g = 1.f / (1.f + __expf(-gamma[0]));
            gp[tid] = __powf(g, (float)tid);
        }
        int wv = tid >> 6, lane = tid & 63;
        int quad = lane >> 4, l15 = lane & 15;
        short8 zero8 = {0, 0, 0, 0, 0, 0, 0, 0};
        float4v czero = {0.f, 0.f, 0.f, 0.f};

        #pragma unroll 1
        for (int it = 0; it < 2; ++it) {
            int bI = blockIdx.x + it * 512;    // virtual block 0..1023
            int head = bI >> 8;
            int mg   = (bI >> 5) & 7;
            int oct  = bI & 31;
            int t = oct * 8 + wv;
            int i = t >> 4, j = t & 15;

            short8 qf = zero8;
            if (quad < 2) {
                const unsigned* qrow = (const unsigned*)(qb + head * 65536
                                        + (t * 16 + l15) * 16) + quad * 4;
                union { unsigned u[4]; short8 s8; } qt;
                #pragma unroll
                for (int q = 0; q < 4; ++q) qt.u[q] = ld_u32g(qrow + q);
                qf = qt.s8;
            }

            const unsigned* kbu = (const unsigned*)(kb  + head * 65536 + mg * 2 * 4096);
            const unsigned* vbu = (const unsigned*)(vtb + head * 65536 + mg * 2 * 4096);
            unsigned kv[16];
            #pragma unroll
            for (int q = 0; q < 4; ++q) kv[q]      = ld_u32g(kbu + tid * 4 + q);
            #pragma unroll
            for (int q = 0; q < 4; ++q) kv[4 + q]  = ld_u32g(vbu + tid * 4 + q);
            #pragma unroll
            for (int q = 0; q < 4; ++q) kv[8 + q]  = ld_u32g(kbu + 2048 + tid * 4 + q);
            #pragma unroll
            for (int q = 0; q < 4; ++q) kv[12 + q] = ld_u32g(vbu + 2048 + tid * 4 + q);
            __syncthreads();                   // prev-iter LDS readers done
            #pragma unroll
            for (int q = 0; q < 4; ++q) {
                ((unsigned*)KSH)[tid * 4 + q]        = kv[q];
                ((unsigned*)VSH)[tid * 4 + q]        = kv[4 + q];
                ((unsigned*)(KSH + 4096))[tid * 4 + q] = kv[8 + q];
                ((unsigned*)(VSH + 4096))[tid * 4 + q] = kv[12 + q];
            }
            __syncthreads();                   // gp + both slabs ready

            float wd[4];
            #pragma unroll
            for (int r = 0; r < 4; ++r)
                wd[r] = gp[abs(l15 - (quad * 4 + r))] * 1.4426950408889634f;  // log2e

            float4v O = czero;
            #pragma unroll
            for (int mm = 0; mm < 2; ++mm) {
                int m = mg * 2 + mm;
                const unsigned short* kk = KSH + mm * 4096;
                const unsigned short* vv = VSH + mm * 4096;
                int eim = abs(i - m);
                #pragma unroll
                for (int np = 0; np < 8; ++np) {
                    union { unsigned u[4]; short8 s8; } a2u;
                    #pragma unroll
                    for (int s = 0; s < 2; ++s) {
                        int n = np * 2 + s;
                        short8 a1 = zero8;
                        if (quad < 2)
                            a1 = *(const short8*)(kk + n * 256 + l15 * 16 + quad * 8);
                        float4v d1 = __builtin_amdgcn_mfma_f32_16x16x32_bf16(a1, qf, czero, 0, 0, 0);
                        float smn = gp[eim + abs(j - n)];        // wave-uniform
                        float e0 = __builtin_amdgcn_exp2f(d1[0] * smn * wd[0]);
                        float e1 = __builtin_amdgcn_exp2f(d1[1] * smn * wd[1]);
                        float e2 = __builtin_amdgcn_exp2f(d1[2] * smn * wd[2]);
                        float e3 = __builtin_amdgcn_exp2f(d1[3] * smn * wd[3]);
                        float sm = e0 + e1 + e2 + e3;
                        sm += __shfl_xor(sm, 16);
                        sm += __shfl_xor(sm, 32);
                        float inv = __builtin_amdgcn_rcpf(sm);
                        union { float f; unsigned u; } p0, p1, p2, p3;
                        p0.f = e0 * inv; p1.f = e1 * inv;
                        p2.f = e2 * inv; p3.f = e3 * inv;
                        a2u.u[s * 2]     = ((p0.u + 0x8000u) >> 16) | ((p1.u + 0x8000u) & 0xFFFF0000u);
                        a2u.u[s * 2 + 1] = ((p2.u + 0x8000u) >> 16) | ((p3.u + 0x8000u) & 0xFFFF0000u);
                    }
                    short8 b2 = *(const short8*)(vv + np * 512 + l15 * 32 + quad * 8);
                    O = __builtin_amdgcn_mfma_f32_16x16x32_bf16(a2u.s8, b2, O, 0, 0, 0);
                }
            }

            float* aop = aoall + mg * CN + (head * 16 + l15) * 4096 + t * 16 + quad * 4;
            #pragma unroll
            for (int r = 0; r < 4; ++r) st_f32g(aop + r, O[r]);
        }
    }
    grid_bar(arrive, release, 3);

    // ================= Phase D: projection =================
    if (blockIdx.x < 256) {
        unsigned short* Bt = (unsigned short*)lds_raw;      // [16][PTP]
        int d   = blockIdx.x >> 4;
        int p16 = blockIdx.x & 15;
        int tid = threadIdx.x;
        bool act = tid < 256;

        if (act) {   // stage: sum 8 partials -> bf16 Bt[px][ci]
            int px = tid & 15, cig = (tid >> 4) & 15;
            int gbase = d * 256 + p16 * 16 + px;
            #pragma unroll
            for (int cc = 0; cc < 4; ++cc) {
                int ci = cig * 4 + cc;
                int ga = ci * 4096 + gbase;
                float v = 0.f;
                #pragma unroll
                for (int k = 0; k < 8; ++k) v += ld_f32g(aoall + k * CN + ga);
                Bt[px * PTP + ci] = f2bf(v);
            }
        }
        __syncthreads();

        if (act) {
            int wv = (tid >> 6) & 3, lane = tid & 63;
            int quad = lane >> 4, l15 = lane & 15;
            float4v czero = {0.f, 0.f, 0.f, 0.f};
            float4v acc = czero;

            short8 af[2];
            const float* wsrc = w_proj + (wv * 16 + l15) * 64 + quad * 8;
            #pragma unroll
            for (int ks = 0; ks < 2; ++ks) {
                float4 wa = *(const float4*)(wsrc + ks * 32);
                float4 wb = *(const float4*)(wsrc + ks * 32 + 4);
                short8 a8 = {(short)f2bf(wa.x), (short)f2bf(wa.y), (short)f2bf(wa.z),
                             (short)f2bf(wa.w), (short)f2bf(wb.x), (short)f2bf(wb.y),
                             (short)f2bf(wb.z), (short)f2bf(wb.w)};
                af[ks] = a8;
            }
            const unsigned short* brow = Bt + l15 * PTP + quad * 8;
            #pragma unroll
            for (int ks = 0; ks < 2; ++ks) {
                short4v lo = *(const short4v*)(brow + ks * 32);
                short4v hi = *(const short4v*)(brow + ks * 32 + 4);
                short8 bf8 = {lo[0], lo[1], lo[2], lo[3], hi[0], hi[1], hi[2], hi[3]};
                acc = __builtin_amdgcn_mfma_f32_16x16x32_bf16(af[ks], bf8, acc, 0, 0, 0);
            }

            int p = d * 256 + p16 * 16 + l15;
            #pragma unroll
            for (int r = 0; r < 4; ++r) {
                int oc = wv * 16 + quad * 4 + r;
                out[oc * 4096 + p] = acc[r] + b_proj[oc];   // normal store: kernel-end release
            }
        }
    }
}

// ---------------------------------------------------------------------------
extern "C" void kernel_launch(void* const* d_in, const int* in_sizes, int n_in,
                              void* d_out, int out_size, void* d_ws, size_t ws_size,
                              hipStream_t stream) {
    const float* x      = (const float*)d_in[0];
    const float* gamma  = (const float*)d_in[1];
    const float* w_sp   = (const float*)d_in[2];
    const float* b_sp   = (const float*)d_in[3];
    const float* w_spec = (const float*)d_in[4];
    const float* b_spec = (const float*)d_in[5];
    const float* w_qkv  = (const float*)d_in[6];
    const float* b_qkv  = (const float*)d_in[7];
    const float* w_proj = (const float*)d_in[8];
    const float* b_proj = (const float*)d_in[9];
    float* out = (float*)d_out;
    float* ws = (float*)d_ws;

    // barrier flags past all workspace tensors (they end at 11.5*CN floats):
    // arrive: 512 x 128B lines; release: 64 x 128B lines after it.
    int* arrive  = (int*)(ws + 12 * CN);
    int* release = arrive + 512 * 32;
    hipMemsetAsync(arrive, 0, (512 + 64) * 128, stream);   // re-zeroed every replay

    mega_kernel<<<dim3(512), dim3(512), 0, stream>>>(
        x, gamma, w_sp, b_sp, w_spec, b_spec, w_qkv, b_qkv, w_proj, b_proj,
        out, ws, arrive, release);
}

// Round 4
// 130.992 us; speedup vs baseline: 2.2267x; 1.1154x over previous
//
#include <hip/hip_runtime.h>
#include <math.h>

// Problem constants: B=1, C=64, D=H=W=16, HEADS=4, HD=16
#define CN   262144        // C * 4096 floats per [C, D, H, W] tensor
#define BTP 196            // qkv/conv Bt row stride in bf16
#define PTP 68             // proj Bt row stride in bf16

typedef __attribute__((ext_vector_type(8))) short short8;   // 8 bf16 (4 VGPRs)
typedef __attribute__((ext_vector_type(4))) short short4v;  // 8 B
typedef __attribute__((ext_vector_type(4))) float float4v;  // MFMA C/D

static __device__ __forceinline__ unsigned short f2bf(float f) {
    union { float f; unsigned u; } v; v.f = f;
    unsigned r = (v.u + 0x7FFFu + ((v.u >> 16) & 1u)) >> 16;   // RNE
    return (unsigned short)r;
}

// ---------------------------------------------------------------------------
// Producer-side L2-bypass (device-coherent) stores for inter-stage tensors.
// R4 insight: CONSUMERS can use normal vectorized loads. At dispatch start
// L1/L2 are invalid; inter-stage lines are only touched via sc1 before the
// barrier, so a post-barrier normal load MUST miss to the coherence point
// (fresh data) and may then cache it — the data is immutable after the
// barrier. This restores float4/short8 coalescing + L2 reuse while keeping
// the fence-free barrier (no buffer_wbl2/inv anywhere).
static __device__ __forceinline__ void st_u32g(void* p, unsigned v) {
    __hip_atomic_store((unsigned*)p, v, __ATOMIC_RELAXED,
                       __HIP_MEMORY_SCOPE_AGENT);
}
static __device__ __forceinline__ void st_u64g(void* p, unsigned long long v) {
    __hip_atomic_store((unsigned long long*)p, v, __ATOMIC_RELAXED,
                       __HIP_MEMORY_SCOPE_AGENT);
}
static __device__ __forceinline__ void st_f32g(void* p, float v) {
    __hip_atomic_store((float*)p, v, __ATOMIC_RELAXED,
                       __HIP_MEMORY_SCOPE_AGENT);
}

// ---------------------------------------------------------------------------
// Grid barrier v3 (unchanged from R3, which measured ~fence-free cost):
// padded arrive flags (no RMW), block-0 master wave polls 8 flags/lane,
// 64 release replicas. Monotonic phases; flags zeroed by hipMemsetAsync each
// replay. Co-residency: __launch_bounds__(512,4) => 2 blocks/CU x 256 CU.
// Bounded spin: a bug degrades to a wrong answer, not a hang.
#define BAR_LIMIT (1 << 20)

static __device__ __forceinline__ void grid_bar(int* arrive, int* release, int phase) {
    __syncthreads();                       // all block threads arrived; vmcnt drained
    if (blockIdx.x == 0) {
        if (threadIdx.x < 64) {            // master wave
            if (threadIdx.x == 0)
                __hip_atomic_store(&arrive[0], phase,
                                   __ATOMIC_RELAXED, __HIP_MEMORY_SCOPE_AGENT);
            int base = (int)threadIdx.x * 8 * 32;   // 8 padded flags per lane
            int z = 0; bool done = false;
            while (!done && z < BAR_LIMIT) {
                int mn = phase;
                #pragma unroll
                for (int q = 0; q < 8; ++q) {
                    int a = __hip_atomic_load(&arrive[base + q * 32],
                                              __ATOMIC_RELAXED, __HIP_MEMORY_SCOPE_AGENT);
                    mn = (a < mn) ? a : mn;
                }
                done = (mn >= phase);
                if (!done) __builtin_amdgcn_s_sleep(1);
                ++z;
            }
            // reconvergence: all 64 lanes saw their 8 flags => all 512 done
            __hip_atomic_store(&release[(int)threadIdx.x * 32], phase,
                               __ATOMIC_RELAXED, __HIP_MEMORY_SCOPE_AGENT);
        }
        __syncthreads();
    } else {
        if (threadIdx.x == 0) {
            __hip_atomic_store(&arrive[(int)blockIdx.x * 32], phase,
                               __ATOMIC_RELAXED, __HIP_MEMORY_SCOPE_AGENT);
            int* rel = &release[(blockIdx.x & 63) * 32];
            int z = 0;
            while (__hip_atomic_load(rel, __ATOMIC_RELAXED,
                                     __HIP_MEMORY_SCOPE_AGENT) < phase
                   && z < BAR_LIMIT) {
                __builtin_amdgcn_s_sleep(2);
                ++z;
            }
        }
        __syncthreads();
    }
}

// ---------------------------------------------------------------------------
// Mega-kernel v4: 4 phases, 3 grid barriers.
//  A: conv_sp (blocks 0-255) || wfb/bfv fusion prep (blocks 256+)
//  B: spectral+QKV GEMM (384 blocks)
//  C: retention attention — 512 blocks, 4 m-slices each (K in LDS, V direct
//     from global via L2), 4 aoall partials
//  D: projection (256 blocks, sums 4 partials)
__global__ __launch_bounds__(512, 4) void mega_kernel(
        const float* __restrict__ x, const float* __restrict__ gamma,
        const float* __restrict__ w_sp, const float* __restrict__ b_sp,
        const float* __restrict__ w_spec, const float* __restrict__ b_spec,
        const float* __restrict__ w_qkv, const float* __restrict__ b_qkv,
        const float* __restrict__ w_proj, const float* __restrict__ b_proj,
        float* __restrict__ out, float* ws, int* arrive, int* release) {
    // LDS union: conv Bt 6.3KB | qkv Bt 12.5KB | attn KSH 32KB + gp | proj 2.2KB
    __shared__ __align__(16) unsigned char lds_raw[32896];

    float* y1  = ws;                                        // [64][4096] f32
    unsigned short* wfb = (unsigned short*)(ws + CN);       // [192][192] bf16
    float* bfv = ws + CN + 20480;                           // [192] fused bias f32
    unsigned short* qb  = (unsigned short*)(ws + 2 * CN);
    unsigned short* kb  = (unsigned short*)(ws + 2 * CN + CN / 2);
    unsigned short* vtb = (unsigned short*)(ws + 3 * CN);
    float* aoall = ws + 3 * CN + CN / 2;                    // 4 x [64][4096] partials

    // ================= Phase A =================
    if (blockIdx.x < 256) {
        // ---- spatial conv 3x3, A-fragments converted inline from w_sp ----
        unsigned short* Bt = (unsigned short*)lds_raw;      // [16][BTP]
        int d = blockIdx.x >> 4;
        int h = blockIdx.x & 15;
        int tid = threadIdx.x;
        bool act = tid < 256;                               // waves 0-3 active
        int px = tid & 15, cig = (tid >> 4) & 15;

        float rcur[12], rnxt[12];
        #define LOAD_CHUNK(dh_, rr)                                            \
            {                                                                  \
                int hh = h + (dh_) - 1;                                        \
                _Pragma("unroll")                                              \
                for (int cc = 0; cc < 4; ++cc) {                               \
                    int ci = cig * 4 + cc;                                     \
                    const float* xr = x + ci * 4096 + d * 256 + hh * 16;       \
                    _Pragma("unroll")                                          \
                    for (int dw = 0; dw < 3; ++dw) {                           \
                        int ww = px + dw - 1;                                  \
                        float v = 0.f;                                         \
                        if (hh >= 0 && hh <= 15 && ww >= 0 && ww <= 15)        \
                            v = xr[ww];                                        \
                        (rr)[cc * 3 + dw] = v;                                 \
                    }                                                          \
                }                                                              \
            }

        if (act) LOAD_CHUNK(0, rcur);

        int wv = (tid >> 6) & 3, lane = tid & 63;
        int quad = lane >> 4, l15 = lane & 15;
        float4v acc = {0.f, 0.f, 0.f, 0.f};
        // row of w_sp for this lane's co; element kp -> +c*3 + (kp/3)*9 + kp%3
        const float* wrow = w_sp + (wv * 16 + l15) * 576;

        #pragma unroll
        for (int c = 0; c < 3; ++c) {
            __syncthreads();                 // guard Bt reuse across chunks
            if (act) {
                #pragma unroll
                for (int cc = 0; cc < 4; ++cc) {
                    int ci = cig * 4 + cc;
                    Bt[px * BTP + ci * 3 + 0] = f2bf(rcur[cc * 3 + 0]);
                    Bt[px * BTP + ci * 3 + 1] = f2bf(rcur[cc * 3 + 1]);
                    Bt[px * BTP + ci * 3 + 2] = f2bf(rcur[cc * 3 + 2]);
                }
            }
            __syncthreads();
            if (act) {
                if (c < 2) LOAD_CHUNK(c + 1, rnxt);

                const unsigned short* brow = Bt + l15 * BTP + quad * 8;
                #pragma unroll
                for (int ks = 0; ks < 6; ++ks) {
                    short8 af;
                    #pragma unroll
                    for (int j = 0; j < 8; ++j) {
                        int kp = quad * 8 + ks * 32 + j;       // c-independent ci/dw: CSE'd
                        af[j] = (short)f2bf(wrow[c * 3 + (kp / 3) * 9 + (kp % 3)]);
                    }
                    short4v lo = *(const short4v*)(brow + ks * 32);
                    short4v hi = *(const short4v*)(brow + ks * 32 + 4);
                    short8 bf8 = {lo[0], lo[1], lo[2], lo[3], hi[0], hi[1], hi[2], hi[3]};
                    acc = __builtin_amdgcn_mfma_f32_16x16x32_bf16(af, bf8, acc, 0, 0, 0);
                }
                #pragma unroll
                for (int q2 = 0; q2 < 12; ++q2) rcur[q2] = rnxt[q2];
            }
        }

        if (act) {
            int p = d * 256 + h * 16 + l15;
            #pragma unroll
            for (int r = 0; r < 4; ++r) {
                int co = wv * 16 + quad * 4 + r;
                st_f32g(y1 + co * 4096 + p, acc[r] + b_sp[co]);
            }
        }
        #undef LOAD_CHUNK
    } else {
        // ---- wfb/bfv fusion prep (runs concurrently with conv) ----
        int idx = (blockIdx.x - 256) * 512 + threadIdx.x;   // 0..131071
        if (idx < 18432) {                  // wfb as u32 pairs (2 adjacent r)
            int oc = idx / 96;
            int rp = idx % 96;
            int r0 = rp * 2;
            float s0 = 0.f, s1 = 0.f;
            #pragma unroll 8
            for (int ci = 0; ci < 64; ++ci) {
                float wq = w_qkv[oc * 64 + ci];
                s0 += wq * w_spec[ci * 192 + r0];
                s1 += wq * w_spec[ci * 192 + r0 + 1];
            }
            if (oc < 64) { s0 *= 0.25f; s1 *= 0.25f; }
            st_u32g(wfb + oc * 192 + r0,
                    (unsigned)f2bf(s0) | ((unsigned)f2bf(s1) << 16));
        } else if (idx < 18432 + 192) {
            int j = idx - 18432;
            float t = b_qkv[j];
            for (int ci = 0; ci < 64; ++ci) t += w_qkv[j * 64 + ci] * b_spec[ci];
            if (j < 64) t *= 0.25f;
            st_f32g(bfv + j, t);
        }
    }
    grid_bar(arrive, release, 1);

    // ================= Phase B: spectral-conv + QKV GEMM =================
    if (blockIdx.x < 384) {
        unsigned short* Bt = (unsigned short*)lds_raw;      // [32][BTP]
        int bI  = blockIdx.x;            // 384 = 16 d x 8 pq x 3 ocg
        int ocg = bI % 3;                // 0=q 1=k 2=v
        int pq  = (bI / 3) & 7;
        int d   = bI / 24;
        int tid = threadIdx.x;

        {   // stage im2col slab: Bt[px][ci*3+t] = y1[ci][d+t-1][pq*32+px]
            int px  = tid & 31;
            int cig = tid >> 5;          // 0..15 (4 ci each)
            const float* yb = y1 + d * 256 + pq * 32 + px;
            #pragma unroll
            for (int cc = 0; cc < 4; ++cc) {
                int ci = cig * 4 + cc;
                const float* yc = yb + ci * 4096;
                #pragma unroll
                for (int t = 0; t < 3; ++t) {
                    float v = 0.f;
                    if (!((d == 0 && t == 0) || (d == 15 && t == 2)))
                        v = yc[(t - 1) * 256];               // normal load (fresh miss)
                    Bt[px * BTP + ci * 3 + t] = f2bf(v);
                }
            }
        }

        int wv = tid >> 6, lane = tid & 63;
        int quad = lane >> 4, l15 = lane & 15;
        int Mt = wv >> 1;                // 0..3 (= head)
        int nt = wv & 1;                 // N-tile (16 pos)

        short8 af[6];
        {
            const unsigned short* ab = wfb + (ocg * 64 + Mt * 16 + l15) * 192 + quad * 8;
            #pragma unroll
            for (int ks = 0; ks < 6; ++ks) af[ks] = *(const short8*)(ab + ks * 32);
        }
        float bias[4];
        #pragma unroll
        for (int r = 0; r < 4; ++r) bias[r] = bfv[ocg * 64 + Mt * 16 + quad * 4 + r];

        __syncthreads();

        float4v czero = {0.f, 0.f, 0.f, 0.f};
        float4v acc = czero;
        {
            const unsigned short* brow = Bt + (nt * 16 + l15) * BTP + quad * 8;
            #pragma unroll
            for (int ks = 0; ks < 6; ++ks) {
                short4v lo = *(const short4v*)(brow + ks * 32);
                short4v hi = *(const short4v*)(brow + ks * 32 + 4);
                short8 bf8 = {lo[0], lo[1], lo[2], lo[3], hi[0], hi[1], hi[2], hi[3]};
                acc = __builtin_amdgcn_mfma_f32_16x16x32_bf16(af[ks], bf8, acc, 0, 0, 0);
            }
        }

        {   // epilogue: C row = oc_local (quad*4+r), col = pos (l15)
            int p = d * 256 + pq * 32 + nt * 16 + l15;
            if (ocg == 2) {
                // vtb: u16 pairs gathered via lane^1 shfl (kap, kap+1 adjacent)
                int h = (p >> 4) & 15, w0 = p & 15;         // h wave-uniform, w0=l15
                int kap = 8 * (w0 >> 2) + 4 * (h & 1) + (w0 & 3);
                unsigned short* dstb = vtb + ((Mt * 16 + d) * 8 + (h >> 1)) * 512
                                           + (quad * 4) * 32;
                int odd = l15 & 1;
                int kap_e = kap - odd;                      // even kap of the pair
                #pragma unroll
                for (int r = 0; r < 4; ++r) {
                    unsigned self = f2bf(acc[r] + bias[r]);
                    unsigned other = (unsigned)__shfl_xor((int)self, 1) & 0xFFFFu;
                    unsigned pk = odd ? (other | (self << 16)) : (self | (other << 16));
                    if ((r < 2) == (odd != 0)) continue;    // even lanes r=0,1; odd r=2,3
                    st_u32g(dstb + r * 32 + kap_e, pk);
                }
            } else {
                unsigned short* dst = (ocg == 0 ? qb : kb) + Mt * 65536 + p * 16 + quad * 4;
                unsigned t0 = (unsigned)f2bf(acc[0] + bias[0])
                            | ((unsigned)f2bf(acc[1] + bias[1]) << 16);
                unsigned t1 = (unsigned)f2bf(acc[2] + bias[2])
                            | ((unsigned)f2bf(acc[3] + bias[3]) << 16);
                st_u64g(dst, (unsigned long long)t0 | ((unsigned long long)t1 << 32));
            }
        }
    }
    grid_bar(arrive, release, 2);

    // ================= Phase C: retention attention =================
    // 512 blocks, one pass: head = bI>>7, mg = (bI>>5)&3 (4 m-slices), oct.
    // K slabs (4 x 8KB) staged in LDS via normal float4 loads (L2-reused by
    // the 32 oct-blocks sharing (head,mg)); V read direct from global short8
    // (coalesced 1KB/wave, L2-hit). aoall has 4 partials (m ascending order
    // preserved -> same summation order as before).
    {
        unsigned short* KSH = (unsigned short*)lds_raw;          // [4][4096]
        float* gp = (float*)(lds_raw + 32768);                   // [32]
        int tid = threadIdx.x;
        int bI = blockIdx.x;
        int head = bI >> 7;
        int mg   = (bI >> 5) & 3;
        int oct  = bI & 31;

        if (tid < 32) {
            float g = 1.f / (1.f + __expf(-gamma[0]));
            gp[tid] = __powf(g, (float)tid);
        }

        int wv = tid >> 6, lane = tid & 63;
        int quad = lane >> 4, l15 = lane & 15;
        int t = oct * 8 + wv;               // q-tile index (= i*16 + j)
        int i = t >> 4, j = t & 15;

        short8 zero8 = {0, 0, 0, 0, 0, 0, 0, 0};
        float4v czero = {0.f, 0.f, 0.f, 0.f};
        short8 qf = zero8;
        if (quad < 2)
            qf = *(const short8*)(qb + head * 65536 + (t * 16 + l15) * 16 + quad * 8);

        {   // stage 4 K slabs: 32KB / 512 thr = 4 float4 per thread
            const float4* kbh = (const float4*)(kb + head * 65536 + mg * 4 * 4096);
            #pragma unroll
            for (int q = 0; q < 4; ++q)
                ((float4*)KSH)[q * 512 + tid] = kbh[q * 512 + tid];
        }
        __syncthreads();                    // gp + K slabs ready

        float wd[4];
        #pragma unroll
        for (int r = 0; r < 4; ++r)
            wd[r] = gp[abs(l15 - (quad * 4 + r))] * 1.4426950408889634f;   // log2e

        float4v O = czero;
        #pragma unroll 1
        for (int mm = 0; mm < 4; ++mm) {
            int m = mg * 4 + mm;
            const unsigned short* kk = KSH + mm * 4096;
            const unsigned short* vvg = vtb + head * 65536 + m * 4096;
            int eim = abs(i - m);
            #pragma unroll
            for (int np = 0; np < 8; ++np) {
                union { unsigned u[4]; short8 s8; } a2u;
                #pragma unroll
                for (int s = 0; s < 2; ++s) {
                    int n = np * 2 + s;
                    short8 a1 = zero8;
                    if (quad < 2)
                        a1 = *(const short8*)(kk + n * 256 + l15 * 16 + quad * 8);
                    float4v d1 = __builtin_amdgcn_mfma_f32_16x16x32_bf16(a1, qf, czero, 0, 0, 0);
                    float smn = gp[eim + abs(j - n)];        // wave-uniform broadcast
                    float e0 = __builtin_amdgcn_exp2f(d1[0] * smn * wd[0]);
                    float e1 = __builtin_amdgcn_exp2f(d1[1] * smn * wd[1]);
                    float e2 = __builtin_amdgcn_exp2f(d1[2] * smn * wd[2]);
                    float e3 = __builtin_amdgcn_exp2f(d1[3] * smn * wd[3]);
                    float sm = e0 + e1 + e2 + e3;
                    sm += __shfl_xor(sm, 16);
                    sm += __shfl_xor(sm, 32);
                    float inv = __builtin_amdgcn_rcpf(sm);
                    union { float f; unsigned u; } p0, p1, p2, p3;
                    p0.f = e0 * inv; p1.f = e1 * inv;
                    p2.f = e2 * inv; p3.f = e3 * inv;
                    a2u.u[s * 2]     = ((p0.u + 0x8000u) >> 16) | ((p1.u + 0x8000u) & 0xFFFF0000u);
                    a2u.u[s * 2 + 1] = ((p2.u + 0x8000u) >> 16) | ((p3.u + 0x8000u) & 0xFFFF0000u);
                }
                short8 b2 = *(const short8*)(vvg + np * 512 + l15 * 32 + quad * 8);
                O = __builtin_amdgcn_mfma_f32_16x16x32_bf16(a2u.s8, b2, O, 0, 0, 0);
            }
        }

        float* aop = aoall + mg * CN + (head * 16 + l15) * 4096 + t * 16 + quad * 4;
        union { float f[2]; unsigned long long u; } o01, o23;
        o01.f[0] = O[0]; o01.f[1] = O[1];
        o23.f[0] = O[2]; o23.f[1] = O[3];
        st_u64g(aop, o01.u);
        st_u64g(aop + 2, o23.u);
    }
    grid_bar(arrive, release, 3);

    // ================= Phase D: projection =================
    if (blockIdx.x < 256) {
        unsigned short* Bt = (unsigned short*)lds_raw;      // [16][PTP]
        int d   = blockIdx.x >> 4;
        int p16 = blockIdx.x & 15;
        int tid = threadIdx.x;
        bool act = tid < 256;

        if (act) {   // stage: sum 4 partials -> bf16 Bt[px][ci]
            int px = tid & 15, cig = (tid >> 4) & 15;
            int gbase = d * 256 + p16 * 16 + px;
            #pragma unroll
            for (int cc = 0; cc < 4; ++cc) {
                int ci = cig * 4 + cc;
                int ga = ci * 4096 + gbase;
                float v = 0.f;
                #pragma unroll
                for (int k = 0; k < 4; ++k) v += aoall[k * CN + ga];   // normal loads
                Bt[px * PTP + ci] = f2bf(v);
            }
        }
        __syncthreads();

        if (act) {
            int wv = (tid >> 6) & 3, lane = tid & 63;
            int quad = lane >> 4, l15 = lane & 15;
            float4v czero = {0.f, 0.f, 0.f, 0.f};
            float4v acc = czero;

            short8 af[2];
            const float* wsrc = w_proj + (wv * 16 + l15) * 64 + quad * 8;
            #pragma unroll
            for (int ks = 0; ks < 2; ++ks) {
                float4 wa = *(const float4*)(wsrc + ks * 32);
                float4 wb = *(const float4*)(wsrc + ks * 32 + 4);
                short8 a8 = {(short)f2bf(wa.x), (short)f2bf(wa.y), (short)f2bf(wa.z),
                             (short)f2bf(wa.w), (short)f2bf(wb.x), (short)f2bf(wb.y),
                             (short)f2bf(wb.z), (short)f2bf(wb.w)};
                af[ks] = a8;
            }
            const unsigned short* brow = Bt + l15 * PTP + quad * 8;
            #pragma unroll
            for (int ks = 0; ks < 2; ++ks) {
                short4v lo = *(const short4v*)(brow + ks * 32);
                short4v hi = *(const short4v*)(brow + ks * 32 + 4);
                short8 bf8 = {lo[0], lo[1], lo[2], lo[3], hi[0], hi[1], hi[2], hi[3]};
                acc = __builtin_amdgcn_mfma_f32_16x16x32_bf16(af[ks], bf8, acc, 0, 0, 0);
            }

            int p = d * 256 + p16 * 16 + l15;
            #pragma unroll
            for (int r = 0; r < 4; ++r) {
                int oc = wv * 16 + quad * 4 + r;
                out[oc * 4096 + p] = acc[r] + b_proj[oc];   // normal store: kernel-end release
            }
        }
    }
}

// ---------------------------------------------------------------------------
extern "C" void kernel_launch(void* const* d_in, const int* in_sizes, int n_in,
                              void* d_out, int out_size, void* d_ws, size_t ws_size,
                              hipStream_t stream) {
    const float* x      = (const float*)d_in[0];
    const float* gamma  = (const float*)d_in[1];
    const float* w_sp   = (const float*)d_in[2];
    const float* b_sp   = (const float*)d_in[3];
    const float* w_spec = (const float*)d_in[4];
    const float* b_spec = (const float*)d_in[5];
    const float* w_qkv  = (const float*)d_in[6];
    const float* b_qkv  = (const float*)d_in[7];
    const float* w_proj = (const float*)d_in[8];
    const float* b_proj = (const float*)d_in[9];
    float* out = (float*)d_out;
    float* ws = (float*)d_ws;

    // barrier flags past all workspace tensors:
    // arrive: 512 x 128B lines; release: 64 x 128B lines after it.
    int* arrive  = (int*)(ws + 12 * CN);
    int* release = arrive + 512 * 32;
    hipMemsetAsync(arrive, 0, (512 + 64) * 128, stream);   // re-zeroed every replay

    mega_kernel<<<dim3(512), dim3(512), 0, stream>>>(
        x, gamma, w_sp, b_sp, w_spec, b_spec, w_qkv, b_qkv, w_proj, b_proj,
        out, ws, arrive, release);
}

// Round 6
// 120.654 us; speedup vs baseline: 2.4175x; 1.0857x over previous
//
#include <hip/hip_runtime.h>
#include <math.h>

// Problem constants: B=1, C=64, D=H=W=16, HEADS=4, HD=16
#define CN   262144        // C * 4096 floats per [C, D, H, W] tensor
#define BTP 196            // qkv/conv Bt row stride in bf16
#define PTP 68             // proj Bt row stride in bf16

typedef __attribute__((ext_vector_type(8))) short short8;   // 8 bf16 (4 VGPRs)
typedef __attribute__((ext_vector_type(4))) short short4v;  // 8 B
typedef __attribute__((ext_vector_type(4))) float float4v;  // MFMA C/D

static __device__ __forceinline__ unsigned short f2bf(float f) {
    union { float f; unsigned u; } v; v.f = f;
    unsigned r = (v.u + 0x7FFFu + ((v.u >> 16) & 1u)) >> 16;   // RNE
    return (unsigned short)r;
}

// ---------------------------------------------------------------------------
// Producer-side L2-bypass (device-coherent) stores for inter-stage tensors.
// Consumers use normal vectorized loads: at dispatch start L1/L2 are invalid,
// inter-stage lines are only ever touched via sc1 before the barrier, so a
// post-barrier normal load must miss to the coherence point (fresh data) and
// may then cache it (data immutable after the barrier). Verified R4: absmax
// bit-identical. Keeps the fence-free barrier (no buffer_wbl2/inv anywhere).
static __device__ __forceinline__ void st_u32g(void* p, unsigned v) {
    __hip_atomic_store((unsigned*)p, v, __ATOMIC_RELAXED,
                       __HIP_MEMORY_SCOPE_AGENT);
}
static __device__ __forceinline__ void st_u64g(void* p, unsigned long long v) {
    __hip_atomic_store((unsigned long long*)p, v, __ATOMIC_RELAXED,
                       __HIP_MEMORY_SCOPE_AGENT);
}
static __device__ __forceinline__ void st_f32g(void* p, float v) {
    __hip_atomic_store((float*)p, v, __ATOMIC_RELAXED,
                       __HIP_MEMORY_SCOPE_AGENT);
}

// ---------------------------------------------------------------------------
// Grid barrier v3 (R3/R4-proven): padded arrive flags (no RMW), block-0
// master wave polls 8 flags/lane, 64 release replicas. Monotonic phases;
// flags zeroed by hipMemsetAsync each replay. Co-residency:
// __launch_bounds__(512,4) => 2 blocks/CU x 256 CU = 512 blocks.
// Bounded spin: a bug degrades to a wrong answer, not a hang.
#define BAR_LIMIT (1 << 20)

static __device__ __forceinline__ void grid_bar(int* arrive, int* release, int phase) {
    __syncthreads();                       // all block threads arrived; vmcnt drained
    if (blockIdx.x == 0) {
        if (threadIdx.x < 64) {            // master wave
            if (threadIdx.x == 0)
                __hip_atomic_store(&arrive[0], phase,
                                   __ATOMIC_RELAXED, __HIP_MEMORY_SCOPE_AGENT);
            int base = (int)threadIdx.x * 8 * 32;   // 8 padded flags per lane
            int z = 0; bool done = false;
            while (!done && z < BAR_LIMIT) {
                int mn = phase;
                #pragma unroll
                for (int q = 0; q < 8; ++q) {
                    int a = __hip_atomic_load(&arrive[base + q * 32],
                                              __ATOMIC_RELAXED, __HIP_MEMORY_SCOPE_AGENT);
                    mn = (a < mn) ? a : mn;
                }
                done = (mn >= phase);
                if (!done) __builtin_amdgcn_s_sleep(1);
                ++z;
            }
            // reconvergence: all 64 lanes saw their 8 flags => all 512 done
            __hip_atomic_store(&release[(int)threadIdx.x * 32], phase,
                               __ATOMIC_RELAXED, __HIP_MEMORY_SCOPE_AGENT);
        }
        __syncthreads();
    } else {
        if (threadIdx.x == 0) {
            __hip_atomic_store(&arrive[(int)blockIdx.x * 32], phase,
                               __ATOMIC_RELAXED, __HIP_MEMORY_SCOPE_AGENT);
            int* rel = &release[(blockIdx.x & 63) * 32];
            int z = 0;
            while (__hip_atomic_load(rel, __ATOMIC_RELAXED,
                                     __HIP_MEMORY_SCOPE_AGENT) < phase
                   && z < BAR_LIMIT) {
                __builtin_amdgcn_s_sleep(2);
                ++z;
            }
        }
        __syncthreads();
    }
}

// ---------------------------------------------------------------------------
// Mega-kernel v5: 5 phases, 4 grid barriers.
//  P0: wsb prep (blocks 0-35; pair-packed coalesced stores). R5 fix: R3/R4's
//      inline per-lane scatter weight loads in conv were ~64-line/instr
//      texture-pipe poison (~15us); a 3us barrier buys them back.
//  P1: conv_sp with vectorized wsb short8 loads (blocks 0-255, r16 code path)
//      || wfb/bfv fusion prep (blocks 256+)
//  P2: spectral+QKV GEMM (384 blocks)
//  P3: retention attention (512 blocks, K in LDS, V via L2, 4 partials)
//  P4: projection (256 blocks)
__global__ __launch_bounds__(512, 4) void mega_kernel(
        const float* __restrict__ x, const float* __restrict__ gamma,
        const float* __restrict__ w_sp, const float* __restrict__ b_sp,
        const float* __restrict__ w_spec, const float* __restrict__ b_spec,
        const float* __restrict__ w_qkv, const float* __restrict__ b_qkv,
        const float* __restrict__ w_proj, const float* __restrict__ b_proj,
        float* __restrict__ out, float* ws, int* arrive, int* release) {
    // LDS union: conv Bt 6.3KB | qkv Bt 12.5KB | attn KSH 32KB + gp | proj 2.2KB
    __shared__ __align__(16) unsigned char lds_raw[32896];

    float* y1  = ws;                                        // [64][4096] f32
    unsigned short* wfb = (unsigned short*)(ws + CN);       // [192][192] bf16
    float* bfv = ws + CN + 20480;                           // [192] fused bias f32
    unsigned short* wsb = (unsigned short*)(ws + CN + 24576); // [3][64][192] bf16
    unsigned short* qb  = (unsigned short*)(ws + 2 * CN);
    unsigned short* kb  = (unsigned short*)(ws + 2 * CN + CN / 2);
    unsigned short* vtb = (unsigned short*)(ws + 3 * CN);
    float* aoall = ws + 3 * CN + CN / 2;                    // 4 x [64][4096] partials

    // ================= P0: wsb weight prep =================
    // wsb[dh][co][kp] = f2bf(w_sp[co*576 + (kp/3)*9 + dh*3 + kp%3]).
    // 2 adjacent kp per thread -> one coalesced u32 sc1 store.
    if (blockIdx.x < 36) {
        int idx2 = blockIdx.x * 512 + threadIdx.x;          // 0..18431
        int idx = idx2 * 2;                                 // even element
        int dh  = idx / 12288;
        int rem = idx % 12288;
        int co  = rem / 192;
        int kp  = rem % 192;                                // even; kp+1 same row
        const float* wrow = w_sp + co * 576 + dh * 3;
        unsigned short e0 = f2bf(wrow[(kp / 3) * 9 + (kp % 3)]);
        unsigned short e1 = f2bf(wrow[((kp + 1) / 3) * 9 + ((kp + 1) % 3)]);
        st_u32g(wsb + idx, (unsigned)e0 | ((unsigned)e1 << 16));
    }
    grid_bar(arrive, release, 1);

    // ================= P1: conv_sp || wfb/bfv prep =================
    if (blockIdx.x < 256) {
        // ---- spatial conv 3x3 as MFMA GEMM (r16-verified code path) ----
        unsigned short* Bt = (unsigned short*)lds_raw;      // [16][BTP]
        int d = blockIdx.x >> 4;
        int h = blockIdx.x & 15;
        int tid = threadIdx.x;
        bool act = tid < 256;                               // waves 0-3 active
        int px = tid & 15, cig = (tid >> 4) & 15;

        float rcur[12], rnxt[12];
        #define LOAD_CHUNK(dh_, rr)                                            \
            {                                                                  \
                int hh = h + (dh_) - 1;                                        \
                _Pragma("unroll")                                              \
                for (int cc = 0; cc < 4; ++cc) {                               \
                    int ci = cig * 4 + cc;                                     \
                    const float* xr = x + ci * 4096 + d * 256 + hh * 16;       \
                    _Pragma("unroll")                                          \
                    for (int dw = 0; dw < 3; ++dw) {                           \
                        int ww = px + dw - 1;                                  \
                        float v = 0.f;                                         \
                        if (hh >= 0 && hh <= 15 && ww >= 0 && ww <= 15)        \
                            v = xr[ww];                                        \
                        (rr)[cc * 3 + dw] = v;                                 \
                    }                                                          \
                }                                                              \
            }

        if (act) LOAD_CHUNK(0, rcur);

        int wv = (tid >> 6) & 3, lane = tid & 63;
        int quad = lane >> 4, l15 = lane & 15;
        float4v acc = {0.f, 0.f, 0.f, 0.f};

        #pragma unroll
        for (int c = 0; c < 3; ++c) {
            __syncthreads();                 // guard Bt reuse across chunks
            if (act) {
                #pragma unroll
                for (int cc = 0; cc < 4; ++cc) {
                    int ci = cig * 4 + cc;
                    Bt[px * BTP + ci * 3 + 0] = f2bf(rcur[cc * 3 + 0]);
                    Bt[px * BTP + ci * 3 + 1] = f2bf(rcur[cc * 3 + 1]);
                    Bt[px * BTP + ci * 3 + 2] = f2bf(rcur[cc * 3 + 2]);
                }
            }
            __syncthreads();
            if (act) {
                if (c < 2) LOAD_CHUNK(c + 1, rnxt);

                const unsigned short* ab = wsb + c * 12288 + (wv * 16 + l15) * 192 + quad * 8;
                const unsigned short* brow = Bt + l15 * BTP + quad * 8;
                #pragma unroll
                for (int ks = 0; ks < 6; ++ks) {
                    short8 af = *(const short8*)(ab + ks * 32);   // vector weight load
                    short4v lo = *(const short4v*)(brow + ks * 32);
                    short4v hi = *(const short4v*)(brow + ks * 32 + 4);
                    short8 bf8 = {lo[0], lo[1], lo[2], lo[3], hi[0], hi[1], hi[2], hi[3]};
                    acc = __builtin_amdgcn_mfma_f32_16x16x32_bf16(af, bf8, acc, 0, 0, 0);
                }
                #pragma unroll
                for (int q2 = 0; q2 < 12; ++q2) rcur[q2] = rnxt[q2];
            }
        }

        if (act) {
            int p = d * 256 + h * 16 + l15;
            #pragma unroll
            for (int r = 0; r < 4; ++r) {
                int co = wv * 16 + quad * 4 + r;
                st_f32g(y1 + co * 4096 + p, acc[r] + b_sp[co]);
            }
        }
        #undef LOAD_CHUNK
    } else {
        // ---- wfb/bfv fusion prep (runs concurrently with conv) ----
        int idx = (blockIdx.x - 256) * 512 + threadIdx.x;   // 0..131071
        if (idx < 18432) {                  // wfb as u32 pairs (2 adjacent r)
            int oc = idx / 96;
            int rp = idx % 96;
            int r0 = rp * 2;
            float s0 = 0.f, s1 = 0.f;
            #pragma unroll 8
            for (int ci = 0; ci < 64; ++ci) {
                float wq = w_qkv[oc * 64 + ci];
                s0 += wq * w_spec[ci * 192 + r0];
                s1 += wq * w_spec[ci * 192 + r0 + 1];
            }
            if (oc < 64) { s0 *= 0.25f; s1 *= 0.25f; }
            st_u32g(wfb + oc * 192 + r0,
                    (unsigned)f2bf(s0) | ((unsigned)f2bf(s1) << 16));
        } else if (idx < 18432 + 192) {
            int j = idx - 18432;
            float t = b_qkv[j];
            for (int ci = 0; ci < 64; ++ci) t += w_qkv[j * 64 + ci] * b_spec[ci];
            if (j < 64) t *= 0.25f;
            st_f32g(bfv + j, t);
        }
    }
    grid_bar(arrive, release, 2);

    // ================= P2: spectral-conv + QKV GEMM =================
    if (blockIdx.x < 384) {
        unsigned short* Bt = (unsigned short*)lds_raw;      // [32][BTP]
        int bI  = blockIdx.x;            // 384 = 16 d x 8 pq x 3 ocg
        int ocg = bI % 3;                // 0=q 1=k 2=v
        int pq  = (bI / 3) & 7;
        int d   = bI / 24;
        int tid = threadIdx.x;

        {   // stage im2col slab: Bt[px][ci*3+t] = y1[ci][d+t-1][pq*32+px]
            int px  = tid & 31;
            int cig = tid >> 5;          // 0..15 (4 ci each)
            const float* yb = y1 + d * 256 + pq * 32 + px;
            #pragma unroll
            for (int cc = 0; cc < 4; ++cc) {
                int ci = cig * 4 + cc;
                const float* yc = yb + ci * 4096;
                #pragma unroll
                for (int t = 0; t < 3; ++t) {
                    float v = 0.f;
                    if (!((d == 0 && t == 0) || (d == 15 && t == 2)))
                        v = yc[(t - 1) * 256];               // normal load (fresh miss)
                    Bt[px * BTP + ci * 3 + t] = f2bf(v);
                }
            }
        }

        int wv = tid >> 6, lane = tid & 63;
        int quad = lane >> 4, l15 = lane & 15;
        int Mt = wv >> 1;                // 0..3 (= head)
        int nt = wv & 1;                 // N-tile (16 pos)

        short8 af[6];
        {
            const unsigned short* ab = wfb + (ocg * 64 + Mt * 16 + l15) * 192 + quad * 8;
            #pragma unroll
            for (int ks = 0; ks < 6; ++ks) af[ks] = *(const short8*)(ab + ks * 32);
        }
        float bias[4];
        #pragma unroll
        for (int r = 0; r < 4; ++r) bias[r] = bfv[ocg * 64 + Mt * 16 + quad * 4 + r];

        __syncthreads();

        float4v czero = {0.f, 0.f, 0.f, 0.f};
        float4v acc = czero;
        {
            const unsigned short* brow = Bt + (nt * 16 + l15) * BTP + quad * 8;
            #pragma unroll
            for (int ks = 0; ks < 6; ++ks) {
                short4v lo = *(const short4v*)(brow + ks * 32);
                short4v hi = *(const short4v*)(brow + ks * 32 + 4);
                short8 bf8 = {lo[0], lo[1], lo[2], lo[3], hi[0], hi[1], hi[2], hi[3]};
                acc = __builtin_amdgcn_mfma_f32_16x16x32_bf16(af[ks], bf8, acc, 0, 0, 0);
            }
        }

        {   // epilogue: C row = oc_local (quad*4+r), col = pos (l15)
            int p = d * 256 + pq * 32 + nt * 16 + l15;
            if (ocg == 2) {
                // vtb: u16 pairs gathered via lane^1 shfl (kap, kap+1 adjacent)
                int h = (p >> 4) & 15, w0 = p & 15;         // h wave-uniform, w0=l15
                int kap = 8 * (w0 >> 2) + 4 * (h & 1) + (w0 & 3);
                unsigned short* dstb = vtb + ((Mt * 16 + d) * 8 + (h >> 1)) * 512
                                           + (quad * 4) * 32;
                int odd = l15 & 1;
                int kap_e = kap - odd;                      // even kap of the pair
                #pragma unroll
                for (int r = 0; r < 4; ++r) {
                    unsigned self = f2bf(acc[r] + bias[r]);
                    unsigned other = (unsigned)__shfl_xor((int)self, 1) & 0xFFFFu;
                    unsigned pk = odd ? (other | (self << 16)) : (self | (other << 16));
                    if ((r < 2) == (odd != 0)) continue;    // even lanes r=0,1; odd r=2,3
                    st_u32g(dstb + r * 32 + kap_e, pk);
                }
            } else {
                unsigned short* dst = (ocg == 0 ? qb : kb) + Mt * 65536 + p * 16 + quad * 4;
                unsigned t0 = (unsigned)f2bf(acc[0] + bias[0])
                            | ((unsigned)f2bf(acc[1] + bias[1]) << 16);
                unsigned t1 = (unsigned)f2bf(acc[2] + bias[2])
                            | ((unsigned)f2bf(acc[3] + bias[3]) << 16);
                st_u64g(dst, (unsigned long long)t0 | ((unsigned long long)t1 << 32));
            }
        }
    }
    grid_bar(arrive, release, 3);

    // ================= P3: retention attention =================
    // 512 blocks, one pass: head = bI>>7, mg = (bI>>5)&3 (4 m-slices), oct.
    // K slabs (4 x 8KB) staged in LDS via normal float4 loads; V direct from
    // global short8 (coalesced, L2-hit). 4 aoall partials, m ascending.
    {
        unsigned short* KSH = (unsigned short*)lds_raw;          // [4][4096]
        float* gp = (float*)(lds_raw + 32768);                   // [32]
        int tid = threadIdx.x;
        int bI = blockIdx.x;
        int head = bI >> 7;
        int mg   = (bI >> 5) & 3;
        int oct  = bI & 31;

        if (tid < 32) {
            float g = 1.f / (1.f + __expf(-gamma[0]));
            gp[tid] = __powf(g, (float)tid);
        }

        int wv = tid >> 6, lane = tid & 63;
        int quad = lane >> 4, l15 = lane & 15;
        int t = oct * 8 + wv;               // q-tile index (= i*16 + j)
        int i = t >> 4, j = t & 15;

        short8 zero8 = {0, 0, 0, 0, 0, 0, 0, 0};
        float4v czero = {0.f, 0.f, 0.f, 0.f};
        short8 qf = zero8;
        if (quad < 2)
            qf = *(const short8*)(qb + head * 65536 + (t * 16 + l15) * 16 + quad * 8);

        {   // stage 4 K slabs: 32KB / 512 thr = 4 float4 per thread
            const float4* kbh = (const float4*)(kb + head * 65536 + mg * 4 * 4096);
            #pragma unroll
            for (int q = 0; q < 4; ++q)
                ((float4*)KSH)[q * 512 + tid] = kbh[q * 512 + tid];
        }
        __syncthreads();                    // gp + K slabs ready

        float wd[4];
        #pragma unroll
        for (int r = 0; r < 4; ++r)
            wd[r] = gp[abs(l15 - (quad * 4 + r))] * 1.4426950408889634f;   // log2e

        float4v O = czero;
        #pragma unroll 1
        for (int mm = 0; mm < 4; ++mm) {
            int m = mg * 4 + mm;
            const unsigned short* kk = KSH + mm * 4096;
            const unsigned short* vvg = vtb + head * 65536 + m * 4096;
            int eim = abs(i - m);
            #pragma unroll
            for (int np = 0; np < 8; ++np) {
                union { unsigned u[4]; short8 s8; } a2u;
                #pragma unroll
                for (int s = 0; s < 2; ++s) {
                    int n = np * 2 + s;
                    short8 a1 = zero8;
                    if (quad < 2)
                        a1 = *(const short8*)(kk + n * 256 + l15 * 16 + quad * 8);
                    float4v d1 = __builtin_amdgcn_mfma_f32_16x16x32_bf16(a1, qf, czero, 0, 0, 0);
                    float smn = gp[eim + abs(j - n)];        // wave-uniform broadcast
                    float e0 = __builtin_amdgcn_exp2f(d1[0] * smn * wd[0]);
                    float e1 = __builtin_amdgcn_exp2f(d1[1] * smn * wd[1]);
                    float e2 = __builtin_amdgcn_exp2f(d1[2] * smn * wd[2]);
                    float e3 = __builtin_amdgcn_exp2f(d1[3] * smn * wd[3]);
                    float sm = e0 + e1 + e2 + e3;
                    sm += __shfl_xor(sm, 16);
                    sm += __shfl_xor(sm, 32);
                    float inv = __builtin_amdgcn_rcpf(sm);
                    union { float f; unsigned u; } p0, p1, p2, p3;
                    p0.f = e0 * inv; p1.f = e1 * inv;
                    p2.f = e2 * inv; p3.f = e3 * inv;
                    a2u.u[s * 2]     = ((p0.u + 0x8000u) >> 16) | ((p1.u + 0x8000u) & 0xFFFF0000u);
                    a2u.u[s * 2 + 1] = ((p2.u + 0x8000u) >> 16) | ((p3.u + 0x8000u) & 0xFFFF0000u);
                }
                short8 b2 = *(const short8*)(vvg + np * 512 + l15 * 32 + quad * 8);
                O = __builtin_amdgcn_mfma_f32_16x16x32_bf16(a2u.s8, b2, O, 0, 0, 0);
            }
        }

        float* aop = aoall + mg * CN + (head * 16 + l15) * 4096 + t * 16 + quad * 4;
        union { float f[2]; unsigned long long u; } o01, o23;
        o01.f[0] = O[0]; o01.f[1] = O[1];
        o23.f[0] = O[2]; o23.f[1] = O[3];
        st_u64g(aop, o01.u);
        st_u64g(aop + 2, o23.u);
    }
    grid_bar(arrive, release, 4);

    // ================= P4: projection =================
    if (blockIdx.x < 256) {
        unsigned short* Bt = (unsigned short*)lds_raw;      // [16][PTP]
        int d   = blockIdx.x >> 4;
        int p16 = blockIdx.x & 15;
        int tid = threadIdx.x;
        bool act = tid < 256;

        if (act) {   // stage: sum 4 partials -> bf16 Bt[px][ci]
            int px = tid & 15, cig = (tid >> 4) & 15;
            int gbase = d * 256 + p16 * 16 + px;
            #pragma unroll
            for (int cc = 0; cc < 4; ++cc) {
                int ci = cig * 4 + cc;
                int ga = ci * 4096 + gbase;
                float v = 0.f;
                #pragma unroll
                for (int k = 0; k < 4; ++k) v += aoall[k * CN + ga];   // normal loads
                Bt[px * PTP + ci] = f2bf(v);
            }
        }
        __syncthreads();

        if (act) {
            int wv = (tid >> 6) & 3, lane = tid & 63;
            int quad = lane >> 4, l15 = lane & 15;
            float4v czero = {0.f, 0.f, 0.f, 0.f};
            float4v acc = czero;

            short8 af[2];
            const float* wsrc = w_proj + (wv * 16 + l15) * 64 + quad * 8;
            #pragma unroll
            for (int ks = 0; ks < 2; ++ks) {
                float4 wa = *(const float4*)(wsrc + ks * 32);
                float4 wb = *(const float4*)(wsrc + ks * 32 + 4);
                short8 a8 = {(short)f2bf(wa.x), (short)f2bf(wa.y), (short)f2bf(wa.z),
                             (short)f2bf(wa.w), (short)f2bf(wb.x), (short)f2bf(wb.y),
                             (short)f2bf(wb.z), (short)f2bf(wb.w)};
                af[ks] = a8;
            }
            const unsigned short* brow = Bt + l15 * PTP + quad * 8;
            #pragma unroll
            for (int ks = 0; ks < 2; ++ks) {
                short4v lo = *(const short4v*)(brow + ks * 32);
                short4v hi = *(const short4v*)(brow + ks * 32 + 4);
                short8 bf8 = {lo[0], lo[1], lo[2], lo[3], hi[0], hi[1], hi[2], hi[3]};
                acc = __builtin_amdgcn_mfma_f32_16x16x32_bf16(af[ks], bf8, acc, 0, 0, 0);
            }

            int p = d * 256 + p16 * 16 + l15;
            #pragma unroll
            for (int r = 0; r < 4; ++r) {
                int oc = wv * 16 + quad * 4 + r;
                out[oc * 4096 + p] = acc[r] + b_proj[oc];   // normal store: kernel-end release
            }
        }
    }
}

// ---------------------------------------------------------------------------
extern "C" void kernel_launch(void* const* d_in, const int* in_sizes, int n_in,
                              void* d_out, int out_size, void* d_ws, size_t ws_size,
                              hipStream_t stream) {
    const float* x      = (const float*)d_in[0];
    const float* gamma  = (const float*)d_in[1];
    const float* w_sp   = (const float*)d_in[2];
    const float* b_sp   = (const float*)d_in[3];
    const float* w_spec = (const float*)d_in[4];
    const float* b_spec = (const float*)d_in[5];
    const float* w_qkv  = (const float*)d_in[6];
    const float* b_qkv  = (const float*)d_in[7];
    const float* w_proj = (const float*)d_in[8];
    const float* b_proj = (const float*)d_in[9];
    float* out = (float*)d_out;
    float* ws = (float*)d_ws;

    // barrier flags past all workspace tensors:
    // arrive: 512 x 128B lines; release: 64 x 128B lines after it.
    int* arrive  = (int*)(ws + 12 * CN);
    int* release = arrive + 512 * 32;
    hipMemsetAsync(arrive, 0, (512 + 64) * 128, stream);   // re-zeroed every replay

    mega_kernel<<<dim3(512), dim3(512), 0, stream>>>(
        x, gamma, w_sp, b_sp, w_spec, b_spec, w_qkv, b_qkv, w_proj, b_proj,
        out, ws, arrive, release);
}